// Round 1
// baseline (1869.095 us; speedup 1.0000x reference)
//
#include <hip/hip_runtime.h>
#include <math.h>

#define EPSF 1e-6f

// ---------------- Kernel B: patch extraction + little_encode (fused) -------
// rows = B*441 = 112896. Block = 256 threads = 2 rows x 128 threads.
// grid = 1764 blocks, 32 iterations each -> 1764*32*2 = 112896 exactly.
__global__ __launch_bounds__(256) void k_little_encode(
    const float* __restrict__ x,      // (256,3,63,63)
    const float* __restrict__ noise,  // (256,441,16) flat
    const float* __restrict__ w1,     // (75,128)
    const float* __restrict__ b1,     // (128)
    const float* __restrict__ w2,     // (128,32)
    const float* __restrict__ b2,     // (32)
    float* __restrict__ nli)          // out: (112896,16)
{
    __shared__ float w1_s[75 * 128];
    __shared__ float w2_s[128 * 32];
    __shared__ float pv[2][76];
    __shared__ float sums[2][4];
    __shared__ float h_s[2][128];
    __shared__ float st_s[2][32];

    int tid = threadIdx.x;
    for (int i = tid; i < 75 * 128; i += 256) w1_s[i] = w1[i];
    for (int i = tid; i < 128 * 32; i += 256) w2_s[i] = w2[i];
    __syncthreads();

    int sub = tid >> 7;   // 0/1 : which row of the pair
    int t   = tid & 127;

    float myb1 = b1[t];
    float myb2 = (t < 32) ? b2[t] : 0.f;

    for (int it = 0; it < 32; ++it) {
        int r = (blockIdx.x * 32 + it) * 2 + sub;   // < 112896 always
        int b = r / 441;
        int p = r - b * 441;
        int pi = p / 21;
        int pj = p - pi * 21;

        // ---- patch values: pv[t] = x_pad + later EPS*sum ----
        float v = 0.f;
        if (t < 75) {
            int c = t / 25, o = t - c * 25;
            int ph = o / 5, pw = o - ph * 5;
            int y  = pi * 3 + ph - 1;
            int xx = pj * 3 + pw - 1;
            if (y >= 0 && y < 63 && xx >= 0 && xx < 63)
                v = x[((size_t)(b * 3 + c) * 63 + y) * 63 + xx];
            pv[sub][t] = v;
        }
        __syncthreads();
        if (t < 3) {
            float s = 0.f;
            #pragma unroll
            for (int i = 0; i < 25; ++i) s += pv[sub][t * 25 + i];
            sums[sub][t] = s;
        }
        __syncthreads();
        if (t < 75) pv[sub][t] = v + EPSF * sums[sub][t / 25];
        __syncthreads();

        // ---- G1: h[n] = relu(p @ w1 + b1), n = t in [0,128) ----
        {
            float acc = myb1;
            #pragma unroll 5
            for (int k = 0; k < 75; ++k)
                acc += pv[sub][k] * w1_s[k * 128 + t];
            h_s[sub][t] = fmaxf(acc, 0.f);
        }
        __syncthreads();

        // ---- G2: stats[n] = h @ w2 + b2, n in [0,32) ----
        if (t < 32) {
            float acc = myb2;
            #pragma unroll 8
            for (int k = 0; k < 128; ++k)
                acc += h_s[sub][k] * w2_s[k * 32 + t];
            st_s[sub][t] = acc;   // NOT relu'd
        }
        __syncthreads();

        // ---- reparam: z_l = noise * exp(0.5*lv) + m ----
        if (t < 16) {
            float m  = st_s[sub][t];
            float lv = st_s[sub][t + 16];
            nli[(size_t)r * 16 + t] =
                noise[(size_t)r * 16 + t] * expf(0.5f * lv) + m;
        }
        __syncthreads();
    }
}

// ---------------- Generic fp32 GEMM: C = act(A @ W + bias) ----------------
// A: M x K (K % 16 == 0, rows 16B-aligned), W: K x N, tile 64x64, 4x4/thread.
template<bool RELU>
__global__ __launch_bounds__(256) void k_gemm(
    const float* __restrict__ A, const float* __restrict__ W,
    const float* __restrict__ bias, float* __restrict__ C,
    int M, int N, int K)
{
    __shared__ float a_s[16][68];
    __shared__ float w_s[16][68];

    int tid = threadIdx.x;
    int tx = tid & 15, ty = tid >> 4;
    int bm = blockIdx.y * 64;
    int bn = blockIdx.x * 64;

    float acc[4][4] = {};

    int ar = tid >> 2;          // 0..63
    int ac = (tid & 3) << 2;    // 0,4,8,12
    int wk = tid >> 4;          // 0..15
    int wn = (tid & 15) << 2;   // 0..60

    for (int k0 = 0; k0 < K; k0 += 16) {
        // stage A (always in-bounds: M multiple of 64, K multiple of 16)
        float4 av = *(const float4*)(A + (size_t)(bm + ar) * K + (k0 + ac));
        a_s[ac + 0][ar] = av.x;
        a_s[ac + 1][ar] = av.y;
        a_s[ac + 2][ar] = av.z;
        a_s[ac + 3][ar] = av.w;
        // stage W (guard columns vs N)
        {
            int gn = bn + wn;
            const float* wp = W + (size_t)(k0 + wk) * N;
            float4 wv;
            if (gn + 3 < N) {
                wv = *(const float4*)(wp + gn);
            } else {
                wv.x = (gn + 0 < N) ? wp[gn + 0] : 0.f;
                wv.y = (gn + 1 < N) ? wp[gn + 1] : 0.f;
                wv.z = (gn + 2 < N) ? wp[gn + 2] : 0.f;
                wv.w = (gn + 3 < N) ? wp[gn + 3] : 0.f;
            }
            *(float4*)&w_s[wk][wn] = wv;
        }
        __syncthreads();
        #pragma unroll
        for (int k = 0; k < 16; ++k) {
            const float4 a = *(const float4*)&a_s[k][ty << 2];
            const float4 w = *(const float4*)&w_s[k][tx << 2];
            acc[0][0] += a.x * w.x; acc[0][1] += a.x * w.y;
            acc[0][2] += a.x * w.z; acc[0][3] += a.x * w.w;
            acc[1][0] += a.y * w.x; acc[1][1] += a.y * w.y;
            acc[1][2] += a.y * w.z; acc[1][3] += a.y * w.w;
            acc[2][0] += a.z * w.x; acc[2][1] += a.z * w.y;
            acc[2][2] += a.z * w.z; acc[2][3] += a.z * w.w;
            acc[3][0] += a.w * w.x; acc[3][1] += a.w * w.y;
            acc[3][2] += a.w * w.z; acc[3][3] += a.w * w.w;
        }
        __syncthreads();
    }

    #pragma unroll
    for (int i = 0; i < 4; ++i) {
        int row = bm + (ty << 2) + i;
        #pragma unroll
        for (int j = 0; j < 4; ++j) {
            int col = bn + (tx << 2) + j;
            if (col < N) {
                float v = acc[i][j] + bias[col];
                if (RELU) v = fmaxf(v, 0.f);
                C[(size_t)row * N + col] = v;
            }
        }
    }
}

// -------- Kernel D': enc GEMM2 + reparam + dec stage1/2 (per-row fused) ----
// grid = 256 (one block per batch row), 256 threads.
__global__ __launch_bounds__(256) void k_mid(
    const float* __restrict__ h_e,     // (256,4096)
    const float* __restrict__ enc_w2,  // (4096,128)
    const float* __restrict__ enc_b2,  // (128)
    const float* __restrict__ noise_z, // (256,64)
    const float* __restrict__ dec_w1,  // (64,32)
    const float* __restrict__ dec_b1,  // (32)
    const float* __restrict__ dec_w2,  // (32,4096)
    const float* __restrict__ dec_b2,  // (4096)
    float* __restrict__ mean_out,      // (256,64)
    float* __restrict__ logvar_out,    // (256,64)
    float* __restrict__ h2)            // (256,4096)
{
    __shared__ float h_row[4096];
    __shared__ float part[256];
    __shared__ float st[128];
    __shared__ float z_s[64];
    __shared__ float h1_s[32];

    int m = blockIdx.x;
    int tid = threadIdx.x;

    const float* hr = h_e + (size_t)m * 4096;
    for (int i = tid; i < 4096; i += 256) h_row[i] = hr[i];
    __syncthreads();

    // stats = relu(h @ enc_w2 + b2): 128 cols, split K in half across threads
    int n = tid & 127;
    int half = tid >> 7;
    {
        float acc = 0.f;
        int k0 = half * 2048;
        for (int k = k0; k < k0 + 2048; ++k)
            acc += h_row[k] * enc_w2[(size_t)k * 128 + n];
        part[tid] = acc;
    }
    __syncthreads();
    if (tid < 128)
        st[tid] = fmaxf(part[tid] + part[tid + 128] + enc_b2[tid], 0.f);
    __syncthreads();

    if (tid < 64) {
        float mean = st[tid], lv = st[tid + 64];
        mean_out[(size_t)m * 64 + tid]   = mean;
        logvar_out[(size_t)m * 64 + tid] = lv;
        z_s[tid] = noise_z[(size_t)m * 64 + tid] * expf(0.5f * lv) + mean;
    }
    __syncthreads();

    // h1 = relu(z @ dec_w1 + b1): 32 cols, K=64
    if (tid < 32) {
        float a = dec_b1[tid];
        #pragma unroll 8
        for (int k = 0; k < 64; ++k) a += z_s[k] * dec_w1[k * 32 + tid];
        h1_s[tid] = fmaxf(a, 0.f);
    }
    __syncthreads();

    // h2 = relu(h1 @ dec_w2 + b2): 4096 cols, K=32
    for (int nn = tid; nn < 4096; nn += 256) {
        float a = dec_b2[nn];
        #pragma unroll 8
        for (int k = 0; k < 32; ++k) a += h1_s[k] * dec_w2[(size_t)k * 4096 + nn];
        h2[(size_t)m * 4096 + nn] = fmaxf(a, 0.f);
    }
}

// ---------------- Kernel G: little_decode + canvas assembly ----------------
// rows = 256*169 = 43264. Block = 2 rows x 128 threads. grid 676 * 32 * 2.
__global__ __launch_bounds__(256) void k_little_decode(
    const float* __restrict__ latent,  // (256,7056) = d_out latent section
    const float* __restrict__ w1,      // (16,128)
    const float* __restrict__ b1,      // (128)
    const float* __restrict__ w2,      // (128,75)
    const float* __restrict__ b2,      // (75)
    float* __restrict__ img)           // (256,3,64,64)
{
    __shared__ float w1_s[16 * 128];
    __shared__ float w2_s[128 * 75];
    __shared__ float z_sh[2][16];
    __shared__ float h_s[2][128];

    int tid = threadIdx.x;
    for (int i = tid; i < 16 * 128; i += 256) w1_s[i] = w1[i];
    for (int i = tid; i < 128 * 75; i += 256) w2_s[i] = w2[i];
    __syncthreads();

    int sub = tid >> 7, t = tid & 127;
    float myb1 = b1[t];
    float myb2 = (t < 75) ? b2[t] : 0.f;

    for (int it = 0; it < 32; ++it) {
        int r = (blockIdx.x * 32 + it) * 2 + sub;  // < 43264 always
        int b  = r / 169;
        int tt = r - b * 169;

        if (t < 16) z_sh[sub][t] = latent[(size_t)b * 7056 + tt * 16 + t];
        __syncthreads();

        // h = relu(z @ ld_w1 + b1), n = t
        {
            float a = myb1;
            #pragma unroll
            for (int k = 0; k < 16; ++k) a += z_sh[sub][k] * w1_s[k * 128 + t];
            h_s[sub][t] = fmaxf(a, 0.f);
        }
        __syncthreads();

        // out = sigmoid(h @ ld_w2 + b2), n = t < 75; scatter into img
        if (t < 75) {
            float a = myb2;
            #pragma unroll 8
            for (int k = 0; k < 128; ++k) a += h_s[sub][k] * w2_s[k * 75 + t];
            float o = 1.f / (1.f + expf(-a));
            int c = t / 25, oo = t - c * 25;
            int ph = oo / 5, pw = oo - ph * 5;
            int ti = tt / 13, tj = tt - ti * 13;
            int y = ti * 5 + ph, xx = tj * 5 + pw;
            if (y < 64 && xx < 64)
                img[(((size_t)b * 3 + c) * 64 + y) * 64 + xx] = o;
        }
        __syncthreads();
    }
}

extern "C" void kernel_launch(void* const* d_in, const int* in_sizes, int n_in,
                              void* d_out, int out_size, void* d_ws, size_t ws_size,
                              hipStream_t stream) {
    const float* x            = (const float*)d_in[0];
    const float* noise_little = (const float*)d_in[1];
    const float* noise_z      = (const float*)d_in[2];
    const float* le_w1        = (const float*)d_in[3];
    const float* le_b1        = (const float*)d_in[4];
    const float* le_w2        = (const float*)d_in[5];
    const float* le_b2        = (const float*)d_in[6];
    const float* ld_w1        = (const float*)d_in[7];
    const float* ld_b1        = (const float*)d_in[8];
    const float* ld_w2        = (const float*)d_in[9];
    const float* ld_b2        = (const float*)d_in[10];
    const float* enc_w1       = (const float*)d_in[11];
    const float* enc_b1       = (const float*)d_in[12];
    const float* enc_w2       = (const float*)d_in[13];
    const float* enc_b2       = (const float*)d_in[14];
    const float* dec_w1       = (const float*)d_in[15];
    const float* dec_b1       = (const float*)d_in[16];
    const float* dec_w2       = (const float*)d_in[17];
    const float* dec_b2       = (const float*)d_in[18];
    const float* dec_w3       = (const float*)d_in[19];
    const float* dec_b3       = (const float*)d_in[20];

    float* out = (float*)d_out;
    // output sections, in return order
    float* latent = out;                       // 256*441*16 = 1806336
    float* mean   = latent + 1806336;          // 16384
    float* logvar = mean + 16384;              // 16384
    float* nli    = logvar + 16384;            // 1806336
    float* img    = nli + 1806336;             // 3145728

    float* h_e = (float*)d_ws;                 // 256*4096
    float* h2  = h_e + 256 * 4096;             // 256*4096

    // 1) patches + little_encode + reparam -> nli (also enc input)
    k_little_encode<<<1764, 256, 0, stream>>>(
        x, noise_little, le_w1, le_b1, le_w2, le_b2, nli);

    // 2) h_e = relu(nli @ enc_w1 + enc_b1)   [256 x 7056 @ 7056 x 4096]
    k_gemm<true><<<dim3(64, 4), 256, 0, stream>>>(
        nli, enc_w1, enc_b1, h_e, 256, 4096, 7056);

    // 3) stats/reparam/dec1/dec2 -> mean, logvar, h2
    k_mid<<<256, 256, 0, stream>>>(
        h_e, enc_w2, enc_b2, noise_z, dec_w1, dec_b1, dec_w2, dec_b2,
        mean, logvar, h2);

    // 4) latent = relu(h2 @ dec_w3 + dec_b3) [256 x 4096 @ 4096 x 7056]
    k_gemm<true><<<dim3(111, 4), 256, 0, stream>>>(
        h2, dec_w3, dec_b3, latent, 256, 7056, 4096);

    // 5) little_decode + canvas crop -> img
    k_little_decode<<<676, 256, 0, stream>>>(
        latent, ld_w1, ld_b1, ld_w2, ld_b2, img);
}

// Round 2
// 744.295 us; speedup vs baseline: 2.5112x; 2.5112x over previous
//
#include <hip/hip_runtime.h>
#include <math.h>

#define EPSF 1e-6f

typedef __attribute__((ext_vector_type(8))) short short8v;
typedef __attribute__((ext_vector_type(4))) float f32x4;
typedef __attribute__((ext_vector_type(4))) unsigned short u16x4;

__device__ __forceinline__ unsigned short f2bf(float f) {
    union { float f; unsigned u; } v; v.f = f;
    return (unsigned short)((v.u + 0x7FFFu + ((v.u >> 16) & 1u)) >> 16);
}
__device__ __forceinline__ int eswz(int r) {
    return ((r & 7) ^ ((r >> 3) & 7)) << 3;   // element (ushort) swizzle
}

// ---------------- Kernel B: patch extraction + little_encode (fused) -------
__global__ __launch_bounds__(256) void k_little_encode(
    const float* __restrict__ x,      // (256,3,63,63)
    const float* __restrict__ noise,  // (256,441,16) flat
    const float* __restrict__ w1,     // (75,128)
    const float* __restrict__ b1,     // (128)
    const float* __restrict__ w2,     // (128,32)
    const float* __restrict__ b2,     // (32)
    float* __restrict__ nli,          // out: (112896,16) fp32 (d_out)
    unsigned short* __restrict__ nli_bf) // out: bf16 copy (ws)
{
    __shared__ float w1_s[75 * 128];
    __shared__ float w2_s[128 * 32];
    __shared__ float pv[2][76];
    __shared__ float sums[2][4];
    __shared__ float h_s[2][128];
    __shared__ float st_s[2][32];

    int tid = threadIdx.x;
    for (int i = tid; i < 75 * 128; i += 256) w1_s[i] = w1[i];
    for (int i = tid; i < 128 * 32; i += 256) w2_s[i] = w2[i];
    __syncthreads();

    int sub = tid >> 7;
    int t   = tid & 127;

    float myb1 = b1[t];
    float myb2 = (t < 32) ? b2[t] : 0.f;

    for (int it = 0; it < 32; ++it) {
        int r = (blockIdx.x * 32 + it) * 2 + sub;
        int b = r / 441;
        int p = r - b * 441;
        int pi = p / 21;
        int pj = p - pi * 21;

        float v = 0.f;
        if (t < 75) {
            int c = t / 25, o = t - c * 25;
            int ph = o / 5, pw = o - ph * 5;
            int y  = pi * 3 + ph - 1;
            int xx = pj * 3 + pw - 1;
            if (y >= 0 && y < 63 && xx >= 0 && xx < 63)
                v = x[((size_t)(b * 3 + c) * 63 + y) * 63 + xx];
            pv[sub][t] = v;
        }
        __syncthreads();
        if (t < 3) {
            float s = 0.f;
            #pragma unroll
            for (int i = 0; i < 25; ++i) s += pv[sub][t * 25 + i];
            sums[sub][t] = s;
        }
        __syncthreads();
        if (t < 75) pv[sub][t] = v + EPSF * sums[sub][t / 25];
        __syncthreads();

        {
            float acc = myb1;
            #pragma unroll 5
            for (int k = 0; k < 75; ++k)
                acc += pv[sub][k] * w1_s[k * 128 + t];
            h_s[sub][t] = fmaxf(acc, 0.f);
        }
        __syncthreads();

        if (t < 32) {
            float acc = myb2;
            #pragma unroll 8
            for (int k = 0; k < 128; ++k)
                acc += h_s[sub][k] * w2_s[k * 32 + t];
            st_s[sub][t] = acc;
        }
        __syncthreads();

        if (t < 16) {
            float m  = st_s[sub][t];
            float lv = st_s[sub][t + 16];
            float z  = noise[(size_t)r * 16 + t] * expf(0.5f * lv) + m;
            nli[(size_t)r * 16 + t] = z;
            nli_bf[(size_t)r * 16 + t] = f2bf(z);
        }
        __syncthreads();
    }
}

// ---------------- bf16 MFMA GEMM: C = act(A(bf16) @ W(fp32->bf16) + bias) --
// A: M x K bf16 row-major. W: K x N fp32. Tile 64x64, BK=64, 4 waves (2x2).
template<bool RELU>
__global__ __launch_bounds__(256) void k_gemm_bf16(
    const unsigned short* __restrict__ A,
    const float* __restrict__ W,
    const float* __restrict__ bias,
    float* __restrict__ C,
    int M, int N, int K)
{
    __shared__ __align__(16) unsigned short As[64 * 64];
    __shared__ __align__(16) unsigned short Bs[64 * 64];

    int t = threadIdx.x;
    int bm = blockIdx.y * 64, bn = blockIdx.x * 64;
    int w = t >> 6, lane = t & 63;
    int wr = w >> 1, wc = w & 1;
    int lr = lane & 15, lg = lane >> 4;

    // staging assignments
    int arow = t >> 2, aseg = t & 3;   // A: 64 rows x 4 segs of 16 elems
    int bu = t & 15, bg = t >> 4;      // W: cols 4*bu..+4, k-rows bg*4..+4

    int T = (K + 63) >> 6;

    uint4 areg0, areg1;
    float wregf[4][4];

    f32x4 acc[2][2];
    #pragma unroll
    for (int i = 0; i < 2; ++i)
        #pragma unroll
        for (int j = 0; j < 2; ++j)
            acc[i][j] = (f32x4){0.f, 0.f, 0.f, 0.f};

    // ---- prefetch tile 0 ----
    #define LOAD_TILE(k0)                                                     \
    do {                                                                      \
        int ak = (k0) + aseg * 16;                                            \
        if (ak < K) {                                                         \
            const uint4* ap = (const uint4*)(A + (size_t)(bm + arow) * K + ak);\
            areg0 = ap[0]; areg1 = ap[1];                                     \
        } else {                                                              \
            areg0 = make_uint4(0,0,0,0); areg1 = make_uint4(0,0,0,0);         \
        }                                                                     \
        int nc = bn + 4 * bu;                                                 \
        _Pragma("unroll")                                                     \
        for (int jj = 0; jj < 4; ++jj) {                                      \
            int kr = (k0) + bg * 4 + jj;                                      \
            if (kr < K && nc < N) {                                           \
                float4 tmp = *(const float4*)(W + (size_t)kr * N + nc);       \
                wregf[jj][0] = tmp.x; wregf[jj][1] = tmp.y;                   \
                wregf[jj][2] = tmp.z; wregf[jj][3] = tmp.w;                   \
            } else {                                                          \
                wregf[jj][0] = 0.f; wregf[jj][1] = 0.f;                       \
                wregf[jj][2] = 0.f; wregf[jj][3] = 0.f;                       \
            }                                                                 \
        }                                                                     \
    } while (0)

    LOAD_TILE(0);

    for (int ti = 0; ti < T; ++ti) {
        __syncthreads();   // prev-tile LDS consumers done (drains our loads)
        // ---- store staged regs to LDS (bf16, swizzled) ----
        {
            int e0 = arow * 64 + aseg * 16;
            int sw = eswz(arow);
            *(uint4*)&As[(e0 ^ sw)]       = areg0;
            *(uint4*)&As[((e0 + 8) ^ sw)] = areg1;
            int nb = 4 * bu;
            #pragma unroll
            for (int c = 0; c < 4; ++c) {
                int n = nb + c;
                u16x4 pk;
                pk.x = f2bf(wregf[0][c]); pk.y = f2bf(wregf[1][c]);
                pk.z = f2bf(wregf[2][c]); pk.w = f2bf(wregf[3][c]);
                *(u16x4*)&Bs[(n * 64 + bg * 4) ^ eswz(n)] = pk;
            }
        }
        __syncthreads();
        if (ti + 1 < T) { int k0n = (ti + 1) << 6; LOAD_TILE(k0n); }

        // ---- compute this tile from LDS ----
        #pragma unroll
        for (int kk = 0; kk < 64; kk += 32) {
            short8v af[2], bfv[2];
            #pragma unroll
            for (int mi = 0; mi < 2; ++mi) {
                int m = wr * 32 + mi * 16 + lr;
                af[mi] = *(const short8v*)&As[(m * 64 + kk + lg * 8) ^ eswz(m)];
            }
            #pragma unroll
            for (int ni = 0; ni < 2; ++ni) {
                int n = wc * 32 + ni * 16 + lr;
                bfv[ni] = *(const short8v*)&Bs[(n * 64 + kk + lg * 8) ^ eswz(n)];
            }
            #pragma unroll
            for (int mi = 0; mi < 2; ++mi)
                #pragma unroll
                for (int ni = 0; ni < 2; ++ni)
                    acc[mi][ni] = __builtin_amdgcn_mfma_f32_16x16x32_bf16(
                        af[mi], bfv[ni], acc[mi][ni], 0, 0, 0);
        }
    }
    #undef LOAD_TILE

    // ---- epilogue: D frag layout col=lane&15, row=(lane>>4)*4+reg ----
    #pragma unroll
    for (int mi = 0; mi < 2; ++mi) {
        #pragma unroll
        for (int ni = 0; ni < 2; ++ni) {
            int col = bn + wc * 32 + ni * 16 + lr;
            if (col < N) {
                float bv = bias[col];
                #pragma unroll
                for (int r = 0; r < 4; ++r) {
                    int row = bm + wr * 32 + mi * 16 + lg * 4 + r;
                    float v = acc[mi][ni][r] + bv;
                    if (RELU) v = fmaxf(v, 0.f);
                    C[(size_t)row * N + col] = v;
                }
            }
        }
    }
}

// ---------- stats partial: psum[m][ks][n] = sum_{k in chunk} h_e[m][k]w2[k][n]
// grid = 256 blocks: (mgroup 0..15) x (ks 0..15). K chunk = 256.
__global__ __launch_bounds__(256) void k_stats_partial(
    const float* __restrict__ h_e,   // (256,4096)
    const float* __restrict__ w2,    // (4096,128)
    float* __restrict__ psum)        // (256,16,128)
{
    __shared__ float hs[16][256];
    int mg = blockIdx.x >> 4;
    int ks = blockIdx.x & 15;
    int t = threadIdx.x;

    for (int i = t; i < 16 * 256; i += 256) {
        int mm = i >> 8, kk = i & 255;
        hs[mm][kk] = h_e[(size_t)(mg * 16 + mm) * 4096 + ks * 256 + kk];
    }
    __syncthreads();

    int n = t & 127, mh = t >> 7;
    float acc[8] = {0.f,0.f,0.f,0.f,0.f,0.f,0.f,0.f};
    const float* w2p = w2 + (size_t)(ks * 256) * 128 + n;
    for (int k = 0; k < 256; ++k) {
        float wv = w2p[(size_t)k * 128];
        #pragma unroll
        for (int mm = 0; mm < 8; ++mm)
            acc[mm] += hs[mh * 8 + mm][k] * wv;
    }
    #pragma unroll
    for (int mm = 0; mm < 8; ++mm) {
        int m = mg * 16 + mh * 8 + mm;
        psum[((size_t)m * 16 + ks) * 128 + n] = acc[mm];
    }
}

// ---------- mid2: reduce psum -> stats(relu) -> mean/logvar/z -> dec1 -> dec2
// grid = 1024 blocks: (m 0..255) x (colchunk 0..3)
__global__ __launch_bounds__(256) void k_mid2(
    const float* __restrict__ psum,
    const float* __restrict__ enc_b2,
    const float* __restrict__ noise_z,
    const float* __restrict__ dec_w1, const float* __restrict__ dec_b1,
    const float* __restrict__ dec_w2, const float* __restrict__ dec_b2,
    float* __restrict__ mean_out, float* __restrict__ logvar_out,
    unsigned short* __restrict__ h2bf)   // (256,4096) bf16
{
    __shared__ float st[128];
    __shared__ float z_s[64];
    __shared__ float h1_s[32];

    int m = blockIdx.x >> 2, ch = blockIdx.x & 3;
    int t = threadIdx.x;

    if (t < 128) {
        float a = enc_b2[t];
        #pragma unroll 4
        for (int ks = 0; ks < 16; ++ks)
            a += psum[((size_t)m * 16 + ks) * 128 + t];
        st[t] = fmaxf(a, 0.f);
    }
    __syncthreads();

    if (t < 64) {
        float mean = st[t], lv = st[t + 64];
        if (ch == 0) {
            mean_out[(size_t)m * 64 + t]   = mean;
            logvar_out[(size_t)m * 64 + t] = lv;
        }
        z_s[t] = noise_z[(size_t)m * 64 + t] * expf(0.5f * lv) + mean;
    }
    __syncthreads();

    if (t < 32) {
        float a = dec_b1[t];
        #pragma unroll 8
        for (int k = 0; k < 64; ++k) a += z_s[k] * dec_w1[k * 32 + t];
        h1_s[t] = fmaxf(a, 0.f);
    }
    __syncthreads();

    #pragma unroll
    for (int j = 0; j < 4; ++j) {
        int nn = ch * 1024 + j * 256 + t;
        float a = dec_b2[nn];
        #pragma unroll 8
        for (int k = 0; k < 32; ++k)
            a += h1_s[k] * dec_w2[(size_t)k * 4096 + nn];
        h2bf[(size_t)m * 4096 + nn] = f2bf(fmaxf(a, 0.f));
    }
}

// ---------------- Kernel G: little_decode + canvas assembly ----------------
__global__ __launch_bounds__(256) void k_little_decode(
    const float* __restrict__ latent,  // (256,7056)
    const float* __restrict__ w1,      // (16,128)
    const float* __restrict__ b1,      // (128)
    const float* __restrict__ w2,      // (128,75)
    const float* __restrict__ b2,      // (75)
    float* __restrict__ img)           // (256,3,64,64)
{
    __shared__ float w1_s[16 * 128];
    __shared__ float w2_s[128 * 75];
    __shared__ float z_sh[2][16];
    __shared__ float h_s[2][128];

    int tid = threadIdx.x;
    for (int i = tid; i < 16 * 128; i += 256) w1_s[i] = w1[i];
    for (int i = tid; i < 128 * 75; i += 256) w2_s[i] = w2[i];
    __syncthreads();

    int sub = tid >> 7, t = tid & 127;
    float myb1 = b1[t];
    float myb2 = (t < 75) ? b2[t] : 0.f;

    for (int it = 0; it < 32; ++it) {
        int r = (blockIdx.x * 32 + it) * 2 + sub;
        int b  = r / 169;
        int tt = r - b * 169;

        if (t < 16) z_sh[sub][t] = latent[(size_t)b * 7056 + tt * 16 + t];
        __syncthreads();

        {
            float a = myb1;
            #pragma unroll
            for (int k = 0; k < 16; ++k) a += z_sh[sub][k] * w1_s[k * 128 + t];
            h_s[sub][t] = fmaxf(a, 0.f);
        }
        __syncthreads();

        if (t < 75) {
            float a = myb2;
            #pragma unroll 8
            for (int k = 0; k < 128; ++k) a += h_s[sub][k] * w2_s[k * 75 + t];
            float o = 1.f / (1.f + expf(-a));
            int c = t / 25, oo = t - c * 25;
            int ph = oo / 5, pw = oo - ph * 5;
            int ti = tt / 13, tj = tt - ti * 13;
            int y = ti * 5 + ph, xx = tj * 5 + pw;
            if (y < 64 && xx < 64)
                img[(((size_t)b * 3 + c) * 64 + y) * 64 + xx] = o;
        }
        __syncthreads();
    }
}

extern "C" void kernel_launch(void* const* d_in, const int* in_sizes, int n_in,
                              void* d_out, int out_size, void* d_ws, size_t ws_size,
                              hipStream_t stream) {
    const float* x            = (const float*)d_in[0];
    const float* noise_little = (const float*)d_in[1];
    const float* noise_z      = (const float*)d_in[2];
    const float* le_w1        = (const float*)d_in[3];
    const float* le_b1        = (const float*)d_in[4];
    const float* le_w2        = (const float*)d_in[5];
    const float* le_b2        = (const float*)d_in[6];
    const float* ld_w1        = (const float*)d_in[7];
    const float* ld_b1        = (const float*)d_in[8];
    const float* ld_w2        = (const float*)d_in[9];
    const float* ld_b2        = (const float*)d_in[10];
    const float* enc_w1       = (const float*)d_in[11];
    const float* enc_b1       = (const float*)d_in[12];
    const float* enc_w2       = (const float*)d_in[13];
    const float* enc_b2       = (const float*)d_in[14];
    const float* dec_w1       = (const float*)d_in[15];
    const float* dec_b1       = (const float*)d_in[16];
    const float* dec_w2       = (const float*)d_in[17];
    const float* dec_b2       = (const float*)d_in[18];
    const float* dec_w3       = (const float*)d_in[19];
    const float* dec_b3       = (const float*)d_in[20];

    float* out = (float*)d_out;
    float* latent = out;                       // 1,806,336
    float* mean   = latent + 1806336;          // 16,384
    float* logvar = mean + 16384;              // 16,384
    float* nli    = logvar + 16384;            // 1,806,336
    float* img    = nli + 1806336;             // 3,145,728

    // h_e (256x4096 fp32, 1,048,576 floats) parked in latent region;
    // consumed by k_stats_partial, then latent fully overwritten by GEMM3.
    float* h_e = latent;

    // ws layout (7.44 MB total)
    unsigned short* nli_bf = (unsigned short*)d_ws;                       // 3,612,672 B
    float* psum = (float*)((char*)d_ws + 3612672);                        // 2,097,152 B
    unsigned short* h2bf = (unsigned short*)((char*)d_ws + 5709824);      // 2,097,152 B

    // 1) patches + little_encode + reparam
    k_little_encode<<<1764, 256, 0, stream>>>(
        x, noise_little, le_w1, le_b1, le_w2, le_b2, nli, nli_bf);

    // 2) h_e = relu(nli @ enc_w1 + b1)  [256x7056 @ 7056x4096]  bf16 MFMA
    k_gemm_bf16<true><<<dim3(64, 4), 256, 0, stream>>>(
        nli_bf, enc_w1, enc_b1, h_e, 256, 4096, 7056);

    // 3a) psum = partial(h_e @ enc_w2)
    k_stats_partial<<<256, 256, 0, stream>>>(h_e, enc_w2, psum);

    // 3b) stats reduce + reparam + dec1 + dec2 -> mean, logvar, h2(bf16)
    k_mid2<<<1024, 256, 0, stream>>>(
        psum, enc_b2, noise_z, dec_w1, dec_b1, dec_w2, dec_b2,
        mean, logvar, h2bf);

    // 4) latent = relu(h2 @ dec_w3 + b3)  [256x4096 @ 4096x7056]  bf16 MFMA
    k_gemm_bf16<true><<<dim3(111, 4), 256, 0, stream>>>(
        h2bf, dec_w3, dec_b3, latent, 256, 7056, 4096);

    // 5) little_decode + canvas crop -> img
    k_little_decode<<<676, 256, 0, stream>>>(
        latent, ld_w1, ld_b1, ld_w2, ld_b2, img);
}

// Round 3
// 273.527 us; speedup vs baseline: 6.8333x; 2.7211x over previous
//
#include <hip/hip_runtime.h>
#include <math.h>

#define EPSF 1e-6f

typedef __attribute__((ext_vector_type(8))) short short8v;
typedef __attribute__((ext_vector_type(4))) float f32x4;
typedef __attribute__((ext_vector_type(4))) unsigned short u16x4;

__device__ __forceinline__ unsigned short f2bf(float f) {
    union { float f; unsigned u; } v; v.f = f;
    return (unsigned short)((v.u + 0x7FFFu + ((v.u >> 16) & 1u)) >> 16);
}
// XOR swizzle for 128-ushort-wide rows (16B-slot granularity, conflict-free
// for b128 reads of 16 consecutive rows at the same k-base; bijective per row)
__device__ __forceinline__ int swe(int row, int k) {
    return (row << 7) + (k ^ ((row & 7) << 3));
}
// same for 64-ushort-wide rows
__device__ __forceinline__ int swe64(int row, int k) {
    return (row << 6) + (k ^ ((row & 7) << 3));
}
__device__ __forceinline__ int eswz(int r) {
    return ((r & 7) ^ ((r >> 3) & 7)) << 3;
}

// ================= little_encode via MFMA =================
// 128 rows/block, grid 882. G1: P(128x96)@w1(96x128) relu -> H
// G2: H(128x128)@w2(128x32) -> stats -> reparam -> nli (f32 + bf16)
__global__ __launch_bounds__(256) void k_little_encode_mfma(
    const float* __restrict__ x,      // (256,3,63,63)
    const float* __restrict__ noise,  // (256,441,16)
    const float* __restrict__ w1,     // (75,128)
    const float* __restrict__ b1,     // (128)
    const float* __restrict__ w2,     // (128,32)
    const float* __restrict__ b2,     // (32)
    float* __restrict__ nli,
    unsigned short* __restrict__ nli_bf)
{
    __shared__ __align__(16) unsigned short pS[128 * 128];   // 32 KB [m][k]
    __shared__ __align__(16) unsigned short w1S[128 * 128];  // 32 KB [n][k]
    __shared__ __align__(16) unsigned short hS[128 * 128];   // 32 KB [m][k]
    __shared__ __align__(16) unsigned short w2S[32 * 128];   //  8 KB [n][k]
    __shared__ float b1S[128];
    __shared__ float b2S[32];
    __shared__ float sums[128][4];

    int t = threadIdx.x;

    // ---- zero pS, w1S (pad regions must read as 0) ----
    {
        uint4 z4 = make_uint4(0, 0, 0, 0);
        #pragma unroll
        for (int i = 0; i < 8; ++i) {
            *(uint4*)&pS[(i * 256 + t) * 8]  = z4;
            *(uint4*)&w1S[(i * 256 + t) * 8] = z4;
        }
    }
    __syncthreads();

    // ---- stage w1 transposed bf16 [n][k] ----
    for (int k = (t >> 4); k < 75; k += 16) {
        int n0 = (t & 15) * 8;
        float4 a0 = *(const float4*)(w1 + k * 128 + n0);
        float4 a1 = *(const float4*)(w1 + k * 128 + n0 + 4);
        w1S[swe(n0 + 0, k)] = f2bf(a0.x);
        w1S[swe(n0 + 1, k)] = f2bf(a0.y);
        w1S[swe(n0 + 2, k)] = f2bf(a0.z);
        w1S[swe(n0 + 3, k)] = f2bf(a0.w);
        w1S[swe(n0 + 4, k)] = f2bf(a1.x);
        w1S[swe(n0 + 5, k)] = f2bf(a1.y);
        w1S[swe(n0 + 6, k)] = f2bf(a1.z);
        w1S[swe(n0 + 7, k)] = f2bf(a1.w);
    }
    // ---- stage w2 transposed bf16 [n=32][k=128] ----
    for (int k = (t >> 3); k < 128; k += 32) {
        int n0 = (t & 7) * 4;
        float4 a = *(const float4*)(w2 + k * 32 + n0);
        w2S[swe(n0 + 0, k)] = f2bf(a.x);
        w2S[swe(n0 + 1, k)] = f2bf(a.y);
        w2S[swe(n0 + 2, k)] = f2bf(a.z);
        w2S[swe(n0 + 3, k)] = f2bf(a.w);
    }
    if (t < 128) b1S[t] = b1[t];
    if (t < 32)  b2S[t] = b2[t];

    // ---- patch gather: row = t&127, half = t>>7 (wave-uniform halves) ----
    int row  = t & 127;
    int half = t >> 7;
    int R0 = blockIdx.x * 128 + row;
    int bb = R0 / 441;
    int p  = R0 - bb * 441;
    int pi = p / 21, pj = p - pi * 21;
    const float* xb = x + (size_t)bb * 3 * 63 * 63;

    float v[38];
    {
        float sA = 0.f, sB = 0.f;
        if (half == 0) {
            #pragma unroll
            for (int i = 0; i < 38; ++i) {
                const int k = i;
                const int c = k / 25, o = k % 25, ph = o / 5, pw = o % 5;
                int y = pi * 3 + ph - 1, xx = pj * 3 + pw - 1;
                float val = 0.f;
                if ((unsigned)y < 63u && (unsigned)xx < 63u)
                    val = xb[(c * 63 + y) * 63 + xx];
                v[i] = val;
                if (k < 25) sA += val; else sB += val;
            }
        } else {
            #pragma unroll
            for (int i = 0; i < 37; ++i) {
                const int k = 38 + i;
                const int c = k / 25, o = k % 25, ph = o / 5, pw = o % 5;
                int y = pi * 3 + ph - 1, xx = pj * 3 + pw - 1;
                float val = 0.f;
                if ((unsigned)y < 63u && (unsigned)xx < 63u)
                    val = xb[(c * 63 + y) * 63 + xx];
                v[i] = val;
                if (k < 50) sA += val; else sB += val;
            }
        }
        sums[row][half * 2 + 0] = sA;
        sums[row][half * 2 + 1] = sB;
    }
    __syncthreads();   // sums + weight staging visible
    {
        float c0 = sums[row][0];
        float c1 = sums[row][1] + sums[row][2];
        float c2 = sums[row][3];
        if (half == 0) {
            #pragma unroll
            for (int i = 0; i < 38; ++i) {
                const int k = i;
                float cs = (k < 25) ? c0 : c1;
                pS[swe(row, k)] = f2bf(v[i] + EPSF * cs);
            }
        } else {
            #pragma unroll
            for (int i = 0; i < 37; ++i) {
                const int k = 38 + i;
                float cs = (k < 50) ? c1 : c2;
                pS[swe(row, k)] = f2bf(v[i] + EPSF * cs);
            }
        }
    }
    __syncthreads();   // pS complete

    // ---- MFMA phase: wave w owns rows [w*32, w*32+32) ----
    int w = t >> 6, lane = t & 63, lr = lane & 15, lg = lane >> 4;

    f32x4 acc[2][8];
    #pragma unroll
    for (int mi = 0; mi < 2; ++mi)
        #pragma unroll
        for (int ni = 0; ni < 8; ++ni)
            acc[mi][ni] = (f32x4){0.f, 0.f, 0.f, 0.f};

    #pragma unroll
    for (int ks = 0; ks < 3; ++ks) {            // K = 96 covers 75
        int kb = ks * 32 + lg * 8;
        short8v a0 = *(const short8v*)&pS[swe(w * 32 + lr, kb)];
        short8v a1 = *(const short8v*)&pS[swe(w * 32 + 16 + lr, kb)];
        #pragma unroll
        for (int ni = 0; ni < 8; ++ni) {
            short8v bf = *(const short8v*)&w1S[swe(ni * 16 + lr, kb)];
            acc[0][ni] = __builtin_amdgcn_mfma_f32_16x16x32_bf16(a0, bf, acc[0][ni], 0, 0, 0);
            acc[1][ni] = __builtin_amdgcn_mfma_f32_16x16x32_bf16(a1, bf, acc[1][ni], 0, 0, 0);
        }
    }
    // H = relu(acc + b1) -> hS (wave-local rows, no barrier needed)
    #pragma unroll
    for (int mi = 0; mi < 2; ++mi)
        #pragma unroll
        for (int ni = 0; ni < 8; ++ni) {
            int n = ni * 16 + lr;
            float bv = b1S[n];
            #pragma unroll
            for (int r = 0; r < 4; ++r) {
                int m = w * 32 + mi * 16 + lg * 4 + r;
                hS[swe(m, n)] = f2bf(fmaxf(acc[mi][ni][r] + bv, 0.f));
            }
        }

    f32x4 acc2[2][2];
    #pragma unroll
    for (int mi = 0; mi < 2; ++mi)
        #pragma unroll
        for (int ni = 0; ni < 2; ++ni)
            acc2[mi][ni] = (f32x4){0.f, 0.f, 0.f, 0.f};

    #pragma unroll
    for (int kh = 0; kh < 4; ++kh) {            // K = 128
        int kb = kh * 32 + lg * 8;
        short8v a0 = *(const short8v*)&hS[swe(w * 32 + lr, kb)];
        short8v a1 = *(const short8v*)&hS[swe(w * 32 + 16 + lr, kb)];
        #pragma unroll
        for (int ni = 0; ni < 2; ++ni) {
            short8v bf = *(const short8v*)&w2S[swe(ni * 16 + lr, kb)];
            acc2[0][ni] = __builtin_amdgcn_mfma_f32_16x16x32_bf16(a0, bf, acc2[0][ni], 0, 0, 0);
            acc2[1][ni] = __builtin_amdgcn_mfma_f32_16x16x32_bf16(a1, bf, acc2[1][ni], 0, 0, 0);
        }
    }

    // reparam epilogue: stats col<16 = mean, col>=16 = logvar
    #pragma unroll
    for (int mi = 0; mi < 2; ++mi)
        #pragma unroll
        for (int r = 0; r < 4; ++r) {
            int m = w * 32 + mi * 16 + lg * 4 + r;
            size_t R = (size_t)blockIdx.x * 128 + m;
            float mean = acc2[mi][0][r] + b2S[lr];
            float lv   = acc2[mi][1][r] + b2S[16 + lr];
            float z = noise[R * 16 + lr] * expf(0.5f * lv) + mean;
            nli[R * 16 + lr] = z;
            nli_bf[R * 16 + lr] = f2bf(z);
        }
}

// ================= little_decode via MFMA =================
// 128 rows/block, grid 338. rows = b*169+tt over first 169 patches.
// G1: z(128x16,pad32)@ld_w1 -> relu H ; G2: H@ld_w2(128x75) -> sigmoid -> img
__global__ __launch_bounds__(256) void k_little_decode_mfma(
    const float* __restrict__ latent,  // (256,7056)
    const float* __restrict__ w1,      // (16,128)
    const float* __restrict__ b1,      // (128)
    const float* __restrict__ w2,      // (128,75)
    const float* __restrict__ b2,      // (75)
    float* __restrict__ img)           // (256,3,64,64)
{
    __shared__ __align__(16) unsigned short w1S[128 * 64];   // 16 KB [n][k<=32]
    __shared__ __align__(16) unsigned short hS[128 * 128];   // 32 KB [m][k]
    __shared__ __align__(16) unsigned short w2S[80 * 128];   // 20 KB [n][k]
    __shared__ float b1S[128];
    __shared__ float b2S[80];

    int t = threadIdx.x;

    {   // zero w1S + w2S
        uint4 z4 = make_uint4(0, 0, 0, 0);
        #pragma unroll
        for (int i = 0; i < 4; ++i)
            *(uint4*)&w1S[(i * 256 + t) * 8] = z4;
        #pragma unroll
        for (int i = 0; i < 5; ++i)
            *(uint4*)&w2S[(i * 256 + t) * 8] = z4;
    }
    __syncthreads();

    {   // w1 (16,128) -> w1S[n][k]
        int k = t >> 4;            // 0..15
        int n0 = (t & 15) * 8;
        float4 a0 = *(const float4*)(w1 + k * 128 + n0);
        float4 a1 = *(const float4*)(w1 + k * 128 + n0 + 4);
        w1S[swe64(n0 + 0, k)] = f2bf(a0.x);
        w1S[swe64(n0 + 1, k)] = f2bf(a0.y);
        w1S[swe64(n0 + 2, k)] = f2bf(a0.z);
        w1S[swe64(n0 + 3, k)] = f2bf(a0.w);
        w1S[swe64(n0 + 4, k)] = f2bf(a1.x);
        w1S[swe64(n0 + 5, k)] = f2bf(a1.y);
        w1S[swe64(n0 + 6, k)] = f2bf(a1.z);
        w1S[swe64(n0 + 7, k)] = f2bf(a1.w);
    }
    {   // w2 (128,75) -> w2S[n][k]
        int k = t >> 1;            // 0..127
        int half = t & 1;
        int n0 = half ? 38 : 0, n1 = half ? 75 : 38;
        for (int n = n0; n < n1; ++n)
            w2S[swe(n, k)] = f2bf(w2[k * 75 + n]);
    }
    if (t < 128) b1S[t] = b1[t];
    if (t < 80)  b2S[t] = (t < 75) ? b2[t] : 0.f;
    __syncthreads();

    int w = t >> 6, lane = t & 63, lr = lane & 15, lg = lane >> 4;

    // ---- G1: A fragments straight from global (K real = 16) ----
    f32x4 acc[2][8];
    #pragma unroll
    for (int mi = 0; mi < 2; ++mi)
        #pragma unroll
        for (int ni = 0; ni < 8; ++ni)
            acc[mi][ni] = (f32x4){0.f, 0.f, 0.f, 0.f};

    short8v af[2];
    #pragma unroll
    for (int mi = 0; mi < 2; ++mi) {
        int m = w * 32 + mi * 16 + lr;
        int R = blockIdx.x * 128 + m;
        int b = R / 169, tt = R - 169 * b;
        if (lg < 2) {
            const float* zp = latent + (size_t)b * 7056 + tt * 16 + lg * 8;
            float4 f0 = *(const float4*)(zp);
            float4 f1 = *(const float4*)(zp + 4);
            af[mi][0] = (short)f2bf(f0.x); af[mi][1] = (short)f2bf(f0.y);
            af[mi][2] = (short)f2bf(f0.z); af[mi][3] = (short)f2bf(f0.w);
            af[mi][4] = (short)f2bf(f1.x); af[mi][5] = (short)f2bf(f1.y);
            af[mi][6] = (short)f2bf(f1.z); af[mi][7] = (short)f2bf(f1.w);
        } else {
            af[mi] = (short8v){0,0,0,0,0,0,0,0};
        }
    }
    {
        int kb = lg * 8;   // < 32
        #pragma unroll
        for (int ni = 0; ni < 8; ++ni) {
            short8v bf = *(const short8v*)&w1S[swe64(ni * 16 + lr, kb)];
            acc[0][ni] = __builtin_amdgcn_mfma_f32_16x16x32_bf16(af[0], bf, acc[0][ni], 0, 0, 0);
            acc[1][ni] = __builtin_amdgcn_mfma_f32_16x16x32_bf16(af[1], bf, acc[1][ni], 0, 0, 0);
        }
    }
    // H -> hS (wave-local)
    #pragma unroll
    for (int mi = 0; mi < 2; ++mi)
        #pragma unroll
        for (int ni = 0; ni < 8; ++ni) {
            int n = ni * 16 + lr;
            float bv = b1S[n];
            #pragma unroll
            for (int r = 0; r < 4; ++r) {
                int m = w * 32 + mi * 16 + lg * 4 + r;
                hS[swe(m, n)] = f2bf(fmaxf(acc[mi][ni][r] + bv, 0.f));
            }
        }

    // ---- G2: stats = H @ w2 (N=80, cols>=75 discarded) ----
    f32x4 acc2[2][5];
    #pragma unroll
    for (int mi = 0; mi < 2; ++mi)
        #pragma unroll
        for (int ni = 0; ni < 5; ++ni)
            acc2[mi][ni] = (f32x4){0.f, 0.f, 0.f, 0.f};

    #pragma unroll
    for (int kh = 0; kh < 4; ++kh) {
        int kb = kh * 32 + lg * 8;
        short8v a0 = *(const short8v*)&hS[swe(w * 32 + lr, kb)];
        short8v a1 = *(const short8v*)&hS[swe(w * 32 + 16 + lr, kb)];
        #pragma unroll
        for (int ni = 0; ni < 5; ++ni) {
            short8v bf = *(const short8v*)&w2S[swe(ni * 16 + lr, kb)];
            acc2[0][ni] = __builtin_amdgcn_mfma_f32_16x16x32_bf16(a0, bf, acc2[0][ni], 0, 0, 0);
            acc2[1][ni] = __builtin_amdgcn_mfma_f32_16x16x32_bf16(a1, bf, acc2[1][ni], 0, 0, 0);
        }
    }

    // sigmoid + canvas scatter (crop 65->64)
    #pragma unroll
    for (int mi = 0; mi < 2; ++mi)
        #pragma unroll
        for (int r = 0; r < 4; ++r) {
            int m = w * 32 + mi * 16 + lg * 4 + r;
            int R = blockIdx.x * 128 + m;
            int b = R / 169, tt = R - 169 * b;
            int ti = tt / 13, tj = tt - 13 * ti;
            #pragma unroll
            for (int ni = 0; ni < 5; ++ni) {
                int col = ni * 16 + lr;
                if (col < 75) {
                    float a = acc2[mi][ni][r] + b2S[col];
                    float o = 1.f / (1.f + expf(-a));
                    int c = col / 25, o25 = col - 25 * c;
                    int ph = o25 / 5, pw = o25 - 5 * ph;
                    int y = ti * 5 + ph, xx = tj * 5 + pw;
                    if (y < 64 && xx < 64)
                        img[(((size_t)b * 3 + c) * 64 + y) * 64 + xx] = o;
                }
            }
        }
}

// ---------------- bf16 MFMA GEMM (unchanged, verified) ----------------
template<bool RELU>
__global__ __launch_bounds__(256) void k_gemm_bf16(
    const unsigned short* __restrict__ A,
    const float* __restrict__ W,
    const float* __restrict__ bias,
    float* __restrict__ C,
    int M, int N, int K)
{
    __shared__ __align__(16) unsigned short As[64 * 64];
    __shared__ __align__(16) unsigned short Bs[64 * 64];

    int t = threadIdx.x;
    int bm = blockIdx.y * 64, bn = blockIdx.x * 64;
    int w = t >> 6, lane = t & 63;
    int wr = w >> 1, wc = w & 1;
    int lr = lane & 15, lg = lane >> 4;

    int arow = t >> 2, aseg = t & 3;
    int bu = t & 15, bg = t >> 4;

    int T = (K + 63) >> 6;

    uint4 areg0, areg1;
    float wregf[4][4];

    f32x4 acc[2][2];
    #pragma unroll
    for (int i = 0; i < 2; ++i)
        #pragma unroll
        for (int j = 0; j < 2; ++j)
            acc[i][j] = (f32x4){0.f, 0.f, 0.f, 0.f};

    #define LOAD_TILE(k0)                                                     \
    do {                                                                      \
        int ak = (k0) + aseg * 16;                                            \
        if (ak < K) {                                                         \
            const uint4* ap = (const uint4*)(A + (size_t)(bm + arow) * K + ak);\
            areg0 = ap[0]; areg1 = ap[1];                                     \
        } else {                                                              \
            areg0 = make_uint4(0,0,0,0); areg1 = make_uint4(0,0,0,0);         \
        }                                                                     \
        int nc = bn + 4 * bu;                                                 \
        _Pragma("unroll")                                                     \
        for (int jj = 0; jj < 4; ++jj) {                                      \
            int kr = (k0) + bg * 4 + jj;                                      \
            if (kr < K && nc < N) {                                           \
                float4 tmp = *(const float4*)(W + (size_t)kr * N + nc);       \
                wregf[jj][0] = tmp.x; wregf[jj][1] = tmp.y;                   \
                wregf[jj][2] = tmp.z; wregf[jj][3] = tmp.w;                   \
            } else {                                                          \
                wregf[jj][0] = 0.f; wregf[jj][1] = 0.f;                       \
                wregf[jj][2] = 0.f; wregf[jj][3] = 0.f;                       \
            }                                                                 \
        }                                                                     \
    } while (0)

    LOAD_TILE(0);

    for (int ti = 0; ti < T; ++ti) {
        __syncthreads();
        {
            int e0 = arow * 64 + aseg * 16;
            int sw = eswz(arow);
            *(uint4*)&As[(e0 ^ sw)]       = areg0;
            *(uint4*)&As[((e0 + 8) ^ sw)] = areg1;
            int nb = 4 * bu;
            #pragma unroll
            for (int c = 0; c < 4; ++c) {
                int n = nb + c;
                u16x4 pk;
                pk.x = f2bf(wregf[0][c]); pk.y = f2bf(wregf[1][c]);
                pk.z = f2bf(wregf[2][c]); pk.w = f2bf(wregf[3][c]);
                *(u16x4*)&Bs[(n * 64 + bg * 4) ^ eswz(n)] = pk;
            }
        }
        __syncthreads();
        if (ti + 1 < T) { int k0n = (ti + 1) << 6; LOAD_TILE(k0n); }

        #pragma unroll
        for (int kk = 0; kk < 64; kk += 32) {
            short8v af2[2], bfv[2];
            #pragma unroll
            for (int mi = 0; mi < 2; ++mi) {
                int m = wr * 32 + mi * 16 + lr;
                af2[mi] = *(const short8v*)&As[(m * 64 + kk + lg * 8) ^ eswz(m)];
            }
            #pragma unroll
            for (int ni = 0; ni < 2; ++ni) {
                int n = wc * 32 + ni * 16 + lr;
                bfv[ni] = *(const short8v*)&Bs[(n * 64 + kk + lg * 8) ^ eswz(n)];
            }
            #pragma unroll
            for (int mi = 0; mi < 2; ++mi)
                #pragma unroll
                for (int ni = 0; ni < 2; ++ni)
                    acc[mi][ni] = __builtin_amdgcn_mfma_f32_16x16x32_bf16(
                        af2[mi], bfv[ni], acc[mi][ni], 0, 0, 0);
        }
    }
    #undef LOAD_TILE

    #pragma unroll
    for (int mi = 0; mi < 2; ++mi) {
        #pragma unroll
        for (int ni = 0; ni < 2; ++ni) {
            int col = bn + wc * 32 + ni * 16 + lr;
            if (col < N) {
                float bv = bias[col];
                #pragma unroll
                for (int r = 0; r < 4; ++r) {
                    int row = bm + wr * 32 + mi * 16 + lg * 4 + r;
                    float v = acc[mi][ni][r] + bv;
                    if (RELU) v = fmaxf(v, 0.f);
                    C[(size_t)row * N + col] = v;
                }
            }
        }
    }
}

// ---------- stats partial (unchanged) ----------
__global__ __launch_bounds__(256) void k_stats_partial(
    const float* __restrict__ h_e,
    const float* __restrict__ w2,
    float* __restrict__ psum)
{
    __shared__ float hs[16][256];
    int mg = blockIdx.x >> 4;
    int ks = blockIdx.x & 15;
    int t = threadIdx.x;

    for (int i = t; i < 16 * 256; i += 256) {
        int mm = i >> 8, kk = i & 255;
        hs[mm][kk] = h_e[(size_t)(mg * 16 + mm) * 4096 + ks * 256 + kk];
    }
    __syncthreads();

    int n = t & 127, mh = t >> 7;
    float acc[8] = {0.f,0.f,0.f,0.f,0.f,0.f,0.f,0.f};
    const float* w2p = w2 + (size_t)(ks * 256) * 128 + n;
    for (int k = 0; k < 256; ++k) {
        float wv = w2p[(size_t)k * 128];
        #pragma unroll
        for (int mm = 0; mm < 8; ++mm)
            acc[mm] += hs[mh * 8 + mm][k] * wv;
    }
    #pragma unroll
    for (int mm = 0; mm < 8; ++mm) {
        int m = mg * 16 + mh * 8 + mm;
        psum[((size_t)m * 16 + ks) * 128 + n] = acc[mm];
    }
}

// ---------- mid2 (unchanged) ----------
__global__ __launch_bounds__(256) void k_mid2(
    const float* __restrict__ psum,
    const float* __restrict__ enc_b2,
    const float* __restrict__ noise_z,
    const float* __restrict__ dec_w1, const float* __restrict__ dec_b1,
    const float* __restrict__ dec_w2, const float* __restrict__ dec_b2,
    float* __restrict__ mean_out, float* __restrict__ logvar_out,
    unsigned short* __restrict__ h2bf)
{
    __shared__ float st[128];
    __shared__ float z_s[64];
    __shared__ float h1_s[32];

    int m = blockIdx.x >> 2, ch = blockIdx.x & 3;
    int t = threadIdx.x;

    if (t < 128) {
        float a = enc_b2[t];
        #pragma unroll 4
        for (int ks = 0; ks < 16; ++ks)
            a += psum[((size_t)m * 16 + ks) * 128 + t];
        st[t] = fmaxf(a, 0.f);
    }
    __syncthreads();

    if (t < 64) {
        float mean = st[t], lv = st[t + 64];
        if (ch == 0) {
            mean_out[(size_t)m * 64 + t]   = mean;
            logvar_out[(size_t)m * 64 + t] = lv;
        }
        z_s[t] = noise_z[(size_t)m * 64 + t] * expf(0.5f * lv) + mean;
    }
    __syncthreads();

    if (t < 32) {
        float a = dec_b1[t];
        #pragma unroll 8
        for (int k = 0; k < 64; ++k) a += z_s[k] * dec_w1[k * 32 + t];
        h1_s[t] = fmaxf(a, 0.f);
    }
    __syncthreads();

    #pragma unroll
    for (int j = 0; j < 4; ++j) {
        int nn = ch * 1024 + j * 256 + t;
        float a = dec_b2[nn];
        #pragma unroll 8
        for (int k = 0; k < 32; ++k)
            a += h1_s[k] * dec_w2[(size_t)k * 4096 + nn];
        h2bf[(size_t)m * 4096 + nn] = f2bf(fmaxf(a, 0.f));
    }
}

extern "C" void kernel_launch(void* const* d_in, const int* in_sizes, int n_in,
                              void* d_out, int out_size, void* d_ws, size_t ws_size,
                              hipStream_t stream) {
    const float* x            = (const float*)d_in[0];
    const float* noise_little = (const float*)d_in[1];
    const float* noise_z      = (const float*)d_in[2];
    const float* le_w1        = (const float*)d_in[3];
    const float* le_b1        = (const float*)d_in[4];
    const float* le_w2        = (const float*)d_in[5];
    const float* le_b2        = (const float*)d_in[6];
    const float* ld_w1        = (const float*)d_in[7];
    const float* ld_b1        = (const float*)d_in[8];
    const float* ld_w2        = (const float*)d_in[9];
    const float* ld_b2        = (const float*)d_in[10];
    const float* enc_w1       = (const float*)d_in[11];
    const float* enc_b1       = (const float*)d_in[12];
    const float* enc_w2       = (const float*)d_in[13];
    const float* enc_b2       = (const float*)d_in[14];
    const float* dec_w1       = (const float*)d_in[15];
    const float* dec_b1       = (const float*)d_in[16];
    const float* dec_w2       = (const float*)d_in[17];
    const float* dec_b2       = (const float*)d_in[18];
    const float* dec_w3       = (const float*)d_in[19];
    const float* dec_b3       = (const float*)d_in[20];

    float* out = (float*)d_out;
    float* latent = out;                       // 1,806,336
    float* mean   = latent + 1806336;          // 16,384
    float* logvar = mean + 16384;              // 16,384
    float* nli    = logvar + 16384;            // 1,806,336
    float* img    = nli + 1806336;             // 3,145,728

    float* h_e = latent;   // parked; overwritten by GEMM3 later

    unsigned short* nli_bf = (unsigned short*)d_ws;                       // 3,612,672 B
    float* psum = (float*)((char*)d_ws + 3612672);                        // 2,097,152 B
    unsigned short* h2bf = (unsigned short*)((char*)d_ws + 5709824);      // 2,097,152 B

    // 1) patches + little_encode + reparam (MFMA)
    k_little_encode_mfma<<<882, 256, 0, stream>>>(
        x, noise_little, le_w1, le_b1, le_w2, le_b2, nli, nli_bf);

    // 2) h_e = relu(nli @ enc_w1 + b1)
    k_gemm_bf16<true><<<dim3(64, 4), 256, 0, stream>>>(
        nli_bf, enc_w1, enc_b1, h_e, 256, 4096, 7056);

    // 3a) psum partials
    k_stats_partial<<<256, 256, 0, stream>>>(h_e, enc_w2, psum);

    // 3b) reduce + reparam + dec1 + dec2
    k_mid2<<<1024, 256, 0, stream>>>(
        psum, enc_b2, noise_z, dec_w1, dec_b1, dec_w2, dec_b2,
        mean, logvar, h2bf);

    // 4) latent = relu(h2 @ dec_w3 + b3)
    k_gemm_bf16<true><<<dim3(111, 4), 256, 0, stream>>>(
        h2bf, dec_w3, dec_b3, latent, 256, 7056, 4096);

    // 5) little_decode + canvas (MFMA)
    k_little_decode_mfma<<<338, 256, 0, stream>>>(
        latent, ld_w1, ld_b1, ld_w2, ld_b2, img);
}

// Round 5
// 266.997 us; speedup vs baseline: 7.0004x; 1.0245x over previous
//
#include <hip/hip_runtime.h>
#include <math.h>

#define EPSF 1e-6f

typedef __attribute__((ext_vector_type(8))) short short8v;
typedef __attribute__((ext_vector_type(4))) float f32x4;
typedef __attribute__((ext_vector_type(4))) unsigned short u16x4;

__device__ __forceinline__ unsigned short f2bf(float f) {
    union { float f; unsigned u; } v; v.f = f;
    return (unsigned short)((v.u + 0x7FFFu + ((v.u >> 16) & 1u)) >> 16);
}
// XOR swizzle for [row][128-ushort] LDS tiles (16B granularity)
__device__ __forceinline__ int swe(int row, int k) {
    return (row << 7) + (k ^ ((row & 7) << 3));
}
// XOR swizzle for [row][64-ushort] LDS tiles
__device__ __forceinline__ int swe64(int row, int k) {
    return (row << 6) + (k ^ ((row & 7) << 3));
}

// ================= little_encode via MFMA (unchanged, verified) =============
__global__ __launch_bounds__(256) void k_little_encode_mfma(
    const float* __restrict__ x,
    const float* __restrict__ noise,
    const float* __restrict__ w1,
    const float* __restrict__ b1,
    const float* __restrict__ w2,
    const float* __restrict__ b2,
    float* __restrict__ nli,
    unsigned short* __restrict__ nli_bf)
{
    __shared__ __align__(16) unsigned short pS[128 * 128];
    __shared__ __align__(16) unsigned short w1S[128 * 128];
    __shared__ __align__(16) unsigned short hS[128 * 128];
    __shared__ __align__(16) unsigned short w2S[32 * 128];
    __shared__ float b1S[128];
    __shared__ float b2S[32];
    __shared__ float sums[128][4];

    int t = threadIdx.x;

    {
        uint4 z4 = make_uint4(0, 0, 0, 0);
        #pragma unroll
        for (int i = 0; i < 8; ++i) {
            *(uint4*)&pS[(i * 256 + t) * 8]  = z4;
            *(uint4*)&w1S[(i * 256 + t) * 8] = z4;
        }
    }
    __syncthreads();

    for (int k = (t >> 4); k < 75; k += 16) {
        int n0 = (t & 15) * 8;
        float4 a0 = *(const float4*)(w1 + k * 128 + n0);
        float4 a1 = *(const float4*)(w1 + k * 128 + n0 + 4);
        w1S[swe(n0 + 0, k)] = f2bf(a0.x);
        w1S[swe(n0 + 1, k)] = f2bf(a0.y);
        w1S[swe(n0 + 2, k)] = f2bf(a0.z);
        w1S[swe(n0 + 3, k)] = f2bf(a0.w);
        w1S[swe(n0 + 4, k)] = f2bf(a1.x);
        w1S[swe(n0 + 5, k)] = f2bf(a1.y);
        w1S[swe(n0 + 6, k)] = f2bf(a1.z);
        w1S[swe(n0 + 7, k)] = f2bf(a1.w);
    }
    for (int k = (t >> 3); k < 128; k += 32) {
        int n0 = (t & 7) * 4;
        float4 a = *(const float4*)(w2 + k * 32 + n0);
        w2S[swe(n0 + 0, k)] = f2bf(a.x);
        w2S[swe(n0 + 1, k)] = f2bf(a.y);
        w2S[swe(n0 + 2, k)] = f2bf(a.z);
        w2S[swe(n0 + 3, k)] = f2bf(a.w);
    }
    if (t < 128) b1S[t] = b1[t];
    if (t < 32)  b2S[t] = b2[t];

    int row  = t & 127;
    int half = t >> 7;
    int R0 = blockIdx.x * 128 + row;
    int bb = R0 / 441;
    int p  = R0 - bb * 441;
    int pi = p / 21, pj = p - pi * 21;
    const float* xb = x + (size_t)bb * 3 * 63 * 63;

    float v[38];
    {
        float sA = 0.f, sB = 0.f;
        if (half == 0) {
            #pragma unroll
            for (int i = 0; i < 38; ++i) {
                const int k = i;
                const int c = k / 25, o = k % 25, ph = o / 5, pw = o % 5;
                int y = pi * 3 + ph - 1, xx = pj * 3 + pw - 1;
                float val = 0.f;
                if ((unsigned)y < 63u && (unsigned)xx < 63u)
                    val = xb[(c * 63 + y) * 63 + xx];
                v[i] = val;
                if (k < 25) sA += val; else sB += val;
            }
        } else {
            #pragma unroll
            for (int i = 0; i < 37; ++i) {
                const int k = 38 + i;
                const int c = k / 25, o = k % 25, ph = o / 5, pw = o % 5;
                int y = pi * 3 + ph - 1, xx = pj * 3 + pw - 1;
                float val = 0.f;
                if ((unsigned)y < 63u && (unsigned)xx < 63u)
                    val = xb[(c * 63 + y) * 63 + xx];
                v[i] = val;
                if (k < 50) sA += val; else sB += val;
            }
        }
        sums[row][half * 2 + 0] = sA;
        sums[row][half * 2 + 1] = sB;
    }
    __syncthreads();
    {
        float c0 = sums[row][0];
        float c1 = sums[row][1] + sums[row][2];
        float c2 = sums[row][3];
        if (half == 0) {
            #pragma unroll
            for (int i = 0; i < 38; ++i) {
                const int k = i;
                float cs = (k < 25) ? c0 : c1;
                pS[swe(row, k)] = f2bf(v[i] + EPSF * cs);
            }
        } else {
            #pragma unroll
            for (int i = 0; i < 37; ++i) {
                const int k = 38 + i;
                float cs = (k < 50) ? c1 : c2;
                pS[swe(row, k)] = f2bf(v[i] + EPSF * cs);
            }
        }
    }
    __syncthreads();

    int w = t >> 6, lane = t & 63, lr = lane & 15, lg = lane >> 4;

    f32x4 acc[2][8];
    #pragma unroll
    for (int mi = 0; mi < 2; ++mi)
        #pragma unroll
        for (int ni = 0; ni < 8; ++ni)
            acc[mi][ni] = (f32x4){0.f, 0.f, 0.f, 0.f};

    #pragma unroll
    for (int ks = 0; ks < 3; ++ks) {
        int kb = ks * 32 + lg * 8;
        short8v a0 = *(const short8v*)&pS[swe(w * 32 + lr, kb)];
        short8v a1 = *(const short8v*)&pS[swe(w * 32 + 16 + lr, kb)];
        #pragma unroll
        for (int ni = 0; ni < 8; ++ni) {
            short8v bf = *(const short8v*)&w1S[swe(ni * 16 + lr, kb)];
            acc[0][ni] = __builtin_amdgcn_mfma_f32_16x16x32_bf16(a0, bf, acc[0][ni], 0, 0, 0);
            acc[1][ni] = __builtin_amdgcn_mfma_f32_16x16x32_bf16(a1, bf, acc[1][ni], 0, 0, 0);
        }
    }
    #pragma unroll
    for (int mi = 0; mi < 2; ++mi)
        #pragma unroll
        for (int ni = 0; ni < 8; ++ni) {
            int n = ni * 16 + lr;
            float bv = b1S[n];
            #pragma unroll
            for (int r = 0; r < 4; ++r) {
                int m = w * 32 + mi * 16 + lg * 4 + r;
                hS[swe(m, n)] = f2bf(fmaxf(acc[mi][ni][r] + bv, 0.f));
            }
        }

    f32x4 acc2[2][2];
    #pragma unroll
    for (int mi = 0; mi < 2; ++mi)
        #pragma unroll
        for (int ni = 0; ni < 2; ++ni)
            acc2[mi][ni] = (f32x4){0.f, 0.f, 0.f, 0.f};

    #pragma unroll
    for (int kh = 0; kh < 4; ++kh) {
        int kb = kh * 32 + lg * 8;
        short8v a0 = *(const short8v*)&hS[swe(w * 32 + lr, kb)];
        short8v a1 = *(const short8v*)&hS[swe(w * 32 + 16 + lr, kb)];
        #pragma unroll
        for (int ni = 0; ni < 2; ++ni) {
            short8v bf = *(const short8v*)&w2S[swe(ni * 16 + lr, kb)];
            acc2[0][ni] = __builtin_amdgcn_mfma_f32_16x16x32_bf16(a0, bf, acc2[0][ni], 0, 0, 0);
            acc2[1][ni] = __builtin_amdgcn_mfma_f32_16x16x32_bf16(a1, bf, acc2[1][ni], 0, 0, 0);
        }
    }

    #pragma unroll
    for (int mi = 0; mi < 2; ++mi)
        #pragma unroll
        for (int r = 0; r < 4; ++r) {
            int m = w * 32 + mi * 16 + lg * 4 + r;
            size_t R = (size_t)blockIdx.x * 128 + m;
            float mean = acc2[mi][0][r] + b2S[lr];
            float lv   = acc2[mi][1][r] + b2S[16 + lr];
            float z = noise[R * 16 + lr] * expf(0.5f * lv) + mean;
            nli[R * 16 + lr] = z;
            nli_bf[R * 16 + lr] = f2bf(z);
        }
}

// ================= little_decode via MFMA (unchanged, verified) =============
__global__ __launch_bounds__(256) void k_little_decode_mfma(
    const float* __restrict__ latent,
    const float* __restrict__ w1,
    const float* __restrict__ b1,
    const float* __restrict__ w2,
    const float* __restrict__ b2,
    float* __restrict__ img)
{
    __shared__ __align__(16) unsigned short w1S[128 * 64];
    __shared__ __align__(16) unsigned short hS[128 * 128];
    __shared__ __align__(16) unsigned short w2S[80 * 128];
    __shared__ float b1S[128];
    __shared__ float b2S[80];

    int t = threadIdx.x;

    {
        uint4 z4 = make_uint4(0, 0, 0, 0);
        #pragma unroll
        for (int i = 0; i < 4; ++i)
            *(uint4*)&w1S[(i * 256 + t) * 8] = z4;
        #pragma unroll
        for (int i = 0; i < 5; ++i)
            *(uint4*)&w2S[(i * 256 + t) * 8] = z4;
    }
    __syncthreads();

    {
        int k = t >> 4;
        int n0 = (t & 15) * 8;
        float4 a0 = *(const float4*)(w1 + k * 128 + n0);
        float4 a1 = *(const float4*)(w1 + k * 128 + n0 + 4);
        w1S[swe64(n0 + 0, k)] = f2bf(a0.x);
        w1S[swe64(n0 + 1, k)] = f2bf(a0.y);
        w1S[swe64(n0 + 2, k)] = f2bf(a0.z);
        w1S[swe64(n0 + 3, k)] = f2bf(a0.w);
        w1S[swe64(n0 + 4, k)] = f2bf(a1.x);
        w1S[swe64(n0 + 5, k)] = f2bf(a1.y);
        w1S[swe64(n0 + 6, k)] = f2bf(a1.z);
        w1S[swe64(n0 + 7, k)] = f2bf(a1.w);
    }
    {
        int k = t >> 1;
        int half = t & 1;
        int n0 = half ? 38 : 0, n1 = half ? 75 : 38;
        for (int n = n0; n < n1; ++n)
            w2S[swe(n, k)] = f2bf(w2[k * 75 + n]);
    }
    if (t < 128) b1S[t] = b1[t];
    if (t < 80)  b2S[t] = (t < 75) ? b2[t] : 0.f;
    __syncthreads();

    int w = t >> 6, lane = t & 63, lr = lane & 15, lg = lane >> 4;

    f32x4 acc[2][8];
    #pragma unroll
    for (int mi = 0; mi < 2; ++mi)
        #pragma unroll
        for (int ni = 0; ni < 8; ++ni)
            acc[mi][ni] = (f32x4){0.f, 0.f, 0.f, 0.f};

    short8v af[2];
    #pragma unroll
    for (int mi = 0; mi < 2; ++mi) {
        int m = w * 32 + mi * 16 + lr;
        int R = blockIdx.x * 128 + m;
        int b = R / 169, tt = R - 169 * b;
        if (lg < 2) {
            const float* zp = latent + (size_t)b * 7056 + tt * 16 + lg * 8;
            float4 f0 = *(const float4*)(zp);
            float4 f1 = *(const float4*)(zp + 4);
            af[mi][0] = (short)f2bf(f0.x); af[mi][1] = (short)f2bf(f0.y);
            af[mi][2] = (short)f2bf(f0.z); af[mi][3] = (short)f2bf(f0.w);
            af[mi][4] = (short)f2bf(f1.x); af[mi][5] = (short)f2bf(f1.y);
            af[mi][6] = (short)f2bf(f1.z); af[mi][7] = (short)f2bf(f1.w);
        } else {
            af[mi] = (short8v){0,0,0,0,0,0,0,0};
        }
    }
    {
        int kb = lg * 8;
        #pragma unroll
        for (int ni = 0; ni < 8; ++ni) {
            short8v bf = *(const short8v*)&w1S[swe64(ni * 16 + lr, kb)];
            acc[0][ni] = __builtin_amdgcn_mfma_f32_16x16x32_bf16(af[0], bf, acc[0][ni], 0, 0, 0);
            acc[1][ni] = __builtin_amdgcn_mfma_f32_16x16x32_bf16(af[1], bf, acc[1][ni], 0, 0, 0);
        }
    }
    #pragma unroll
    for (int mi = 0; mi < 2; ++mi)
        #pragma unroll
        for (int ni = 0; ni < 8; ++ni) {
            int n = ni * 16 + lr;
            float bv = b1S[n];
            #pragma unroll
            for (int r = 0; r < 4; ++r) {
                int m = w * 32 + mi * 16 + lg * 4 + r;
                hS[swe(m, n)] = f2bf(fmaxf(acc[mi][ni][r] + bv, 0.f));
            }
        }

    f32x4 acc2[2][5];
    #pragma unroll
    for (int mi = 0; mi < 2; ++mi)
        #pragma unroll
        for (int ni = 0; ni < 5; ++ni)
            acc2[mi][ni] = (f32x4){0.f, 0.f, 0.f, 0.f};

    #pragma unroll
    for (int kh = 0; kh < 4; ++kh) {
        int kb = kh * 32 + lg * 8;
        short8v a0 = *(const short8v*)&hS[swe(w * 32 + lr, kb)];
        short8v a1 = *(const short8v*)&hS[swe(w * 32 + 16 + lr, kb)];
        #pragma unroll
        for (int ni = 0; ni < 5; ++ni) {
            short8v bf = *(const short8v*)&w2S[swe(ni * 16 + lr, kb)];
            acc2[0][ni] = __builtin_amdgcn_mfma_f32_16x16x32_bf16(a0, bf, acc2[0][ni], 0, 0, 0);
            acc2[1][ni] = __builtin_amdgcn_mfma_f32_16x16x32_bf16(a1, bf, acc2[1][ni], 0, 0, 0);
        }
    }

    #pragma unroll
    for (int mi = 0; mi < 2; ++mi)
        #pragma unroll
        for (int r = 0; r < 4; ++r) {
            int m = w * 32 + mi * 16 + lg * 4 + r;
            int R = blockIdx.x * 128 + m;
            int b = R / 169, tt = R - 169 * b;
            int ti = tt / 13, tj = tt - 13 * ti;
            #pragma unroll
            for (int ni = 0; ni < 5; ++ni) {
                int col = ni * 16 + lr;
                if (col < 75) {
                    float a = acc2[mi][ni][r] + b2S[col];
                    float o = 1.f / (1.f + expf(-a));
                    int c = col / 25, o25 = col - 25 * c;
                    int ph = o25 / 5, pw = o25 - 5 * ph;
                    int y = ti * 5 + ph, xx = tj * 5 + pw;
                    if (y < 64 && xx < 64)
                        img[(((size_t)b * 3 + c) * 64 + y) * 64 + xx] = o;
                }
            }
        }
}

// ============ split-K bf16 MFMA GEMM: C(+)= A @ bf16(W), raw partials =======
// A: M=256 x K bf16. W: K x N f32. C: 256 x N f32, PRE-ZEROED.
// Block: BN=64 cols (blockIdx.x), K-chunk (blockIdx.y), 256 thr = 4 waves,
// wave w owns rows [w*64, w*64+64). Atomic-add fp32 epilogue (agent scope).
__global__ __launch_bounds__(256) void k_gemm_splitk(
    const unsigned short* __restrict__ A,
    const float* __restrict__ W,
    float* __restrict__ C,
    int N, int K, int baseSteps)
{
    __shared__ __align__(16) unsigned short As[256 * 64];  // 32 KB
    __shared__ __align__(16) unsigned short Ws[64 * 64];   //  8 KB

    int t = threadIdx.x;
    int bn = blockIdx.x * 64;
    int totalSteps = (K + 63) >> 6;
    int step0 = blockIdx.y * baseSteps;
    int nSteps = totalSteps - step0;
    if (nSteps > baseSteps) nSteps = baseSteps;
    if (nSteps <= 0) return;

    int w = t >> 6, lane = t & 63, lr = lane & 15, lg = lane >> 4;
    int arow = t >> 2, aseg = t & 3;     // A: rows 64j+arow, 16-ushort seg
    int bu = t & 15, bg = t >> 4;        // W: n0=4bu, k-rows 4bg..+3

    uint4 areg[4][2];
    float wregf[4][4];
    const uint4 z4 = make_uint4(0, 0, 0, 0);

    f32x4 acc[4][4];
    #pragma unroll
    for (int i = 0; i < 4; ++i)
        #pragma unroll
        for (int j = 0; j < 4; ++j)
            acc[i][j] = (f32x4){0.f, 0.f, 0.f, 0.f};

    #define LOADT(stepIdx)                                                    \
    do {                                                                      \
        int kk0 = (stepIdx) << 6;                                             \
        int ak = kk0 + aseg * 16;                                             \
        _Pragma("unroll")                                                     \
        for (int j = 0; j < 4; ++j) {                                         \
            int row = j * 64 + arow;                                          \
            if (ak < K) {                                                     \
                const uint4* ap = (const uint4*)(A + (size_t)row * K + ak);   \
                areg[j][0] = ap[0]; areg[j][1] = ap[1];                       \
            } else { areg[j][0] = z4; areg[j][1] = z4; }                      \
        }                                                                     \
        int nc = bn + 4 * bu;                                                 \
        _Pragma("unroll")                                                     \
        for (int jj = 0; jj < 4; ++jj) {                                      \
            int kr = kk0 + bg * 4 + jj;                                       \
            if (kr < K && nc + 3 < N) {                                       \
                float4 tmp = *(const float4*)(W + (size_t)kr * N + nc);       \
                wregf[jj][0] = tmp.x; wregf[jj][1] = tmp.y;                   \
                wregf[jj][2] = tmp.z; wregf[jj][3] = tmp.w;                   \
            } else if (kr < K) {                                              \
                const float* wp = W + (size_t)kr * N;                         \
                wregf[jj][0] = (nc + 0 < N) ? wp[nc + 0] : 0.f;               \
                wregf[jj][1] = (nc + 1 < N) ? wp[nc + 1] : 0.f;               \
                wregf[jj][2] = (nc + 2 < N) ? wp[nc + 2] : 0.f;               \
                wregf[jj][3] = (nc + 3 < N) ? wp[nc + 3] : 0.f;               \
            } else {                                                          \
                wregf[jj][0] = 0.f; wregf[jj][1] = 0.f;                       \
                wregf[jj][2] = 0.f; wregf[jj][3] = 0.f;                       \
            }                                                                 \
        }                                                                     \
    } while (0)

    LOADT(step0);

    for (int ti = 0; ti < nSteps; ++ti) {
        __syncthreads();
        // A -> LDS (swizzled [row][64])
        {
            int kb = aseg * 16;
            #pragma unroll
            for (int j = 0; j < 4; ++j) {
                int row = j * 64 + arow;
                *(uint4*)&As[swe64(row, kb)]     = areg[j][0];
                *(uint4*)&As[swe64(row, kb + 8)] = areg[j][1];
            }
        }
        // W -> LDS bf16 ([n][k] swizzled)
        {
            #pragma unroll
            for (int c = 0; c < 4; ++c) {
                int n = 4 * bu + c;
                u16x4 pk;
                pk.x = f2bf(wregf[0][c]); pk.y = f2bf(wregf[1][c]);
                pk.z = f2bf(wregf[2][c]); pk.w = f2bf(wregf[3][c]);
                *(u16x4*)&Ws[swe64(n, 4 * bg)] = pk;
            }
        }
        __syncthreads();
        if (ti + 1 < nSteps) LOADT(step0 + ti + 1);

        #pragma unroll
        for (int kk = 0; kk < 64; kk += 32) {
            short8v afr[4], bfr[4];
            #pragma unroll
            for (int mi = 0; mi < 4; ++mi)
                afr[mi] = *(const short8v*)&As[swe64(w * 64 + mi * 16 + lr, kk + lg * 8)];
            #pragma unroll
            for (int ni = 0; ni < 4; ++ni)
                bfr[ni] = *(const short8v*)&Ws[swe64(ni * 16 + lr, kk + lg * 8)];
            #pragma unroll
            for (int mi = 0; mi < 4; ++mi)
                #pragma unroll
                for (int ni = 0; ni < 4; ++ni)
                    acc[mi][ni] = __builtin_amdgcn_mfma_f32_16x16x32_bf16(
                        afr[mi], bfr[ni], acc[mi][ni], 0, 0, 0);
        }
    }
    #undef LOADT

    // atomic-add epilogue
    #pragma unroll
    for (int ni = 0; ni < 4; ++ni) {
        int col = bn + ni * 16 + lr;
        if (col < N) {
            #pragma unroll
            for (int mi = 0; mi < 4; ++mi) {
                int row = w * 64 + mi * 16 + lg * 4;
                #pragma unroll
                for (int r = 0; r < 4; ++r)
                    __hip_atomic_fetch_add(&C[(size_t)(row + r) * N + col],
                                           acc[mi][ni][r],
                                           __ATOMIC_RELAXED,
                                           __HIP_MEMORY_SCOPE_AGENT);
            }
        }
    }
}

// ---------- stats partial: applies relu(h_raw + enc_b1) on load ------------
__global__ __launch_bounds__(256) void k_stats_partial(
    const float* __restrict__ h_e,    // RAW (no bias/relu)
    const float* __restrict__ enc_b1, // (4096)
    const float* __restrict__ w2,
    float* __restrict__ psum)
{
    __shared__ float hs[16][256];
    int mg = blockIdx.x >> 4;
    int ks = blockIdx.x & 15;
    int t = threadIdx.x;

    for (int i = t; i < 16 * 256; i += 256) {
        int mm = i >> 8, kk = i & 255;
        hs[mm][kk] = fmaxf(
            h_e[(size_t)(mg * 16 + mm) * 4096 + ks * 256 + kk] + enc_b1[ks * 256 + kk],
            0.f);
    }
    __syncthreads();

    int n = t & 127, mh = t >> 7;
    float acc[8] = {0.f,0.f,0.f,0.f,0.f,0.f,0.f,0.f};
    const float* w2p = w2 + (size_t)(ks * 256) * 128 + n;
    for (int k = 0; k < 256; ++k) {
        float wv = w2p[(size_t)k * 128];
        #pragma unroll
        for (int mm = 0; mm < 8; ++mm)
            acc[mm] += hs[mh * 8 + mm][k] * wv;
    }
    #pragma unroll
    for (int mm = 0; mm < 8; ++mm) {
        int m = mg * 16 + mh * 8 + mm;
        psum[((size_t)m * 16 + ks) * 128 + n] = acc[mm];
    }
}

// ---------- mid2 (unchanged) ----------
__global__ __launch_bounds__(256) void k_mid2(
    const float* __restrict__ psum,
    const float* __restrict__ enc_b2,
    const float* __restrict__ noise_z,
    const float* __restrict__ dec_w1, const float* __restrict__ dec_b1,
    const float* __restrict__ dec_w2, const float* __restrict__ dec_b2,
    float* __restrict__ mean_out, float* __restrict__ logvar_out,
    unsigned short* __restrict__ h2bf)
{
    __shared__ float st[128];
    __shared__ float z_s[64];
    __shared__ float h1_s[32];

    int m = blockIdx.x >> 2, ch = blockIdx.x & 3;
    int t = threadIdx.x;

    if (t < 128) {
        float a = enc_b2[t];
        #pragma unroll 4
        for (int ks = 0; ks < 16; ++ks)
            a += psum[((size_t)m * 16 + ks) * 128 + t];
        st[t] = fmaxf(a, 0.f);
    }
    __syncthreads();

    if (t < 64) {
        float mean = st[t], lv = st[t + 64];
        if (ch == 0) {
            mean_out[(size_t)m * 64 + t]   = mean;
            logvar_out[(size_t)m * 64 + t] = lv;
        }
        z_s[t] = noise_z[(size_t)m * 64 + t] * expf(0.5f * lv) + mean;
    }
    __syncthreads();

    if (t < 32) {
        float a = dec_b1[t];
        #pragma unroll 8
        for (int k = 0; k < 64; ++k) a += z_s[k] * dec_w1[k * 32 + t];
        h1_s[t] = fmaxf(a, 0.f);
    }
    __syncthreads();

    #pragma unroll
    for (int j = 0; j < 4; ++j) {
        int nn = ch * 1024 + j * 256 + t;
        float a = dec_b2[nn];
        #pragma unroll 8
        for (int k = 0; k < 32; ++k)
            a += h1_s[k] * dec_w2[(size_t)k * 4096 + nn];
        h2bf[(size_t)m * 4096 + nn] = f2bf(fmaxf(a, 0.f));
    }
}

// ---------- latent epilogue: latent = relu(raw + dec_b3[col]) in place -----
__global__ __launch_bounds__(256) void k_bias_relu(
    float* __restrict__ buf, const float* __restrict__ bias)
{
    int idx = blockIdx.x * 256 + threadIdx.x;
    #pragma unroll
    for (int j = 0; j < 4; ++j) {
        int f = idx + j * 112896;
        int col4 = f % 1764;
        float4 v = ((float4*)buf)[f];
        float4 b = *(const float4*)(bias + col4 * 4);
        v.x = fmaxf(v.x + b.x, 0.f);
        v.y = fmaxf(v.y + b.y, 0.f);
        v.z = fmaxf(v.z + b.z, 0.f);
        v.w = fmaxf(v.w + b.w, 0.f);
        ((float4*)buf)[f] = v;
    }
}

extern "C" void kernel_launch(void* const* d_in, const int* in_sizes, int n_in,
                              void* d_out, int out_size, void* d_ws, size_t ws_size,
                              hipStream_t stream) {
    const float* x            = (const float*)d_in[0];
    const float* noise_little = (const float*)d_in[1];
    const float* noise_z      = (const float*)d_in[2];
    const float* le_w1        = (const float*)d_in[3];
    const float* le_b1        = (const float*)d_in[4];
    const float* le_w2        = (const float*)d_in[5];
    const float* le_b2        = (const float*)d_in[6];
    const float* ld_w1        = (const float*)d_in[7];
    const float* ld_b1        = (const float*)d_in[8];
    const float* ld_w2        = (const float*)d_in[9];
    const float* ld_b2        = (const float*)d_in[10];
    const float* enc_w1       = (const float*)d_in[11];
    const float* enc_b1       = (const float*)d_in[12];
    const float* enc_w2       = (const float*)d_in[13];
    const float* enc_b2       = (const float*)d_in[14];
    const float* dec_w1       = (const float*)d_in[15];
    const float* dec_b1       = (const float*)d_in[16];
    const float* dec_w2       = (const float*)d_in[17];
    const float* dec_b2       = (const float*)d_in[18];
    const float* dec_w3       = (const float*)d_in[19];
    const float* dec_b3       = (const float*)d_in[20];

    float* out = (float*)d_out;
    float* latent = out;                       // 1,806,336
    float* mean   = latent + 1806336;          // 16,384
    float* logvar = mean + 16384;              // 16,384
    float* nli    = logvar + 16384;            // 1,806,336
    float* img    = nli + 1806336;             // 3,145,728

    float* h_e = latent;   // raw GEMM1 output parked here; wiped before GEMM2

    unsigned short* nli_bf = (unsigned short*)d_ws;                       // 3,612,672 B
    float* psum = (float*)((char*)d_ws + 3612672);                        // 2,097,152 B
    unsigned short* h2bf = (unsigned short*)((char*)d_ws + 5709824);      // 2,097,152 B

    // 0) zero h_e accumulation region (4 MB)
    hipMemsetAsync(h_e, 0, (size_t)256 * 4096 * 4, stream);

    // 1) patches + little_encode + reparam (MFMA)
    k_little_encode_mfma<<<882, 256, 0, stream>>>(
        x, noise_little, le_w1, le_b1, le_w2, le_b2, nli, nli_bf);

    // 2) h_e_raw += nli @ enc_w1   [256x7056 @ 7056x4096] split-K
    k_gemm_splitk<<<dim3(64, 8), 256, 0, stream>>>(
        nli_bf, enc_w1, h_e, 4096, 7056, 14);

    // 3a) psum partials (bias+relu fused on h_e load)
    k_stats_partial<<<256, 256, 0, stream>>>(h_e, enc_b1, enc_w2, psum);

    // 3b) reduce + reparam + dec1 + dec2
    k_mid2<<<1024, 256, 0, stream>>>(
        psum, enc_b2, noise_z, dec_w1, dec_b1, dec_w2, dec_b2,
        mean, logvar, h2bf);

    // 4) zero latent accumulation region (7.2 MB), then split-K GEMM
    hipMemsetAsync(latent, 0, (size_t)1806336 * 4, stream);
    k_gemm_splitk<<<dim3(111, 8), 256, 0, stream>>>(
        h2bf, dec_w3, latent, 7056, 4096, 8);

    // 4b) latent = relu(latent_raw + dec_b3)
    k_bias_relu<<<441, 256, 0, stream>>>(latent, dec_b3);

    // 5) little_decode + canvas (MFMA)
    k_little_decode_mfma<<<338, 256, 0, stream>>>(
        latent, ld_w1, ld_b1, ld_w2, ld_b2, img);
}

// Round 6
// 238.335 us; speedup vs baseline: 7.8423x; 1.1203x over previous
//
#include <hip/hip_runtime.h>
#include <math.h>

#define EPSF 1e-6f

typedef __attribute__((ext_vector_type(8))) short short8v;
typedef __attribute__((ext_vector_type(4))) float f32x4;
typedef __attribute__((ext_vector_type(4))) unsigned short u16x4;

__device__ __forceinline__ unsigned short f2bf(float f) {
    union { float f; unsigned u; } v; v.f = f;
    return (unsigned short)((v.u + 0x7FFFu + ((v.u >> 16) & 1u)) >> 16);
}
// XOR swizzle for [row][128-ushort] LDS tiles (16B granularity)
__device__ __forceinline__ int swe(int row, int k) {
    return (row << 7) + (k ^ ((row & 7) << 3));
}
// XOR swizzle for [row][64-ushort] LDS tiles
__device__ __forceinline__ int swe64(int row, int k) {
    return (row << 6) + (k ^ ((row & 7) << 3));
}

// ================= little_encode via MFMA (unchanged, verified) =============
__global__ __launch_bounds__(256) void k_little_encode_mfma(
    const float* __restrict__ x,
    const float* __restrict__ noise,
    const float* __restrict__ w1,
    const float* __restrict__ b1,
    const float* __restrict__ w2,
    const float* __restrict__ b2,
    float* __restrict__ nli,
    unsigned short* __restrict__ nli_bf)
{
    __shared__ __align__(16) unsigned short pS[128 * 128];
    __shared__ __align__(16) unsigned short w1S[128 * 128];
    __shared__ __align__(16) unsigned short hS[128 * 128];
    __shared__ __align__(16) unsigned short w2S[32 * 128];
    __shared__ float b1S[128];
    __shared__ float b2S[32];
    __shared__ float sums[128][4];

    int t = threadIdx.x;

    {
        uint4 z4 = make_uint4(0, 0, 0, 0);
        #pragma unroll
        for (int i = 0; i < 8; ++i) {
            *(uint4*)&pS[(i * 256 + t) * 8]  = z4;
            *(uint4*)&w1S[(i * 256 + t) * 8] = z4;
        }
    }
    __syncthreads();

    for (int k = (t >> 4); k < 75; k += 16) {
        int n0 = (t & 15) * 8;
        float4 a0 = *(const float4*)(w1 + k * 128 + n0);
        float4 a1 = *(const float4*)(w1 + k * 128 + n0 + 4);
        w1S[swe(n0 + 0, k)] = f2bf(a0.x);
        w1S[swe(n0 + 1, k)] = f2bf(a0.y);
        w1S[swe(n0 + 2, k)] = f2bf(a0.z);
        w1S[swe(n0 + 3, k)] = f2bf(a0.w);
        w1S[swe(n0 + 4, k)] = f2bf(a1.x);
        w1S[swe(n0 + 5, k)] = f2bf(a1.y);
        w1S[swe(n0 + 6, k)] = f2bf(a1.z);
        w1S[swe(n0 + 7, k)] = f2bf(a1.w);
    }
    for (int k = (t >> 3); k < 128; k += 32) {
        int n0 = (t & 7) * 4;
        float4 a = *(const float4*)(w2 + k * 32 + n0);
        w2S[swe(n0 + 0, k)] = f2bf(a.x);
        w2S[swe(n0 + 1, k)] = f2bf(a.y);
        w2S[swe(n0 + 2, k)] = f2bf(a.z);
        w2S[swe(n0 + 3, k)] = f2bf(a.w);
    }
    if (t < 128) b1S[t] = b1[t];
    if (t < 32)  b2S[t] = b2[t];

    int row  = t & 127;
    int half = t >> 7;
    int R0 = blockIdx.x * 128 + row;
    int bb = R0 / 441;
    int p  = R0 - bb * 441;
    int pi = p / 21, pj = p - pi * 21;
    const float* xb = x + (size_t)bb * 3 * 63 * 63;

    float v[38];
    {
        float sA = 0.f, sB = 0.f;
        if (half == 0) {
            #pragma unroll
            for (int i = 0; i < 38; ++i) {
                const int k = i;
                const int c = k / 25, o = k % 25, ph = o / 5, pw = o % 5;
                int y = pi * 3 + ph - 1, xx = pj * 3 + pw - 1;
                float val = 0.f;
                if ((unsigned)y < 63u && (unsigned)xx < 63u)
                    val = xb[(c * 63 + y) * 63 + xx];
                v[i] = val;
                if (k < 25) sA += val; else sB += val;
            }
        } else {
            #pragma unroll
            for (int i = 0; i < 37; ++i) {
                const int k = 38 + i;
                const int c = k / 25, o = k % 25, ph = o / 5, pw = o % 5;
                int y = pi * 3 + ph - 1, xx = pj * 3 + pw - 1;
                float val = 0.f;
                if ((unsigned)y < 63u && (unsigned)xx < 63u)
                    val = xb[(c * 63 + y) * 63 + xx];
                v[i] = val;
                if (k < 50) sA += val; else sB += val;
            }
        }
        sums[row][half * 2 + 0] = sA;
        sums[row][half * 2 + 1] = sB;
    }
    __syncthreads();
    {
        float c0 = sums[row][0];
        float c1 = sums[row][1] + sums[row][2];
        float c2 = sums[row][3];
        if (half == 0) {
            #pragma unroll
            for (int i = 0; i < 38; ++i) {
                const int k = i;
                float cs = (k < 25) ? c0 : c1;
                pS[swe(row, k)] = f2bf(v[i] + EPSF * cs);
            }
        } else {
            #pragma unroll
            for (int i = 0; i < 37; ++i) {
                const int k = 38 + i;
                float cs = (k < 50) ? c1 : c2;
                pS[swe(row, k)] = f2bf(v[i] + EPSF * cs);
            }
        }
    }
    __syncthreads();

    int w = t >> 6, lane = t & 63, lr = lane & 15, lg = lane >> 4;

    f32x4 acc[2][8];
    #pragma unroll
    for (int mi = 0; mi < 2; ++mi)
        #pragma unroll
        for (int ni = 0; ni < 8; ++ni)
            acc[mi][ni] = (f32x4){0.f, 0.f, 0.f, 0.f};

    #pragma unroll
    for (int ks = 0; ks < 3; ++ks) {
        int kb = ks * 32 + lg * 8;
        short8v a0 = *(const short8v*)&pS[swe(w * 32 + lr, kb)];
        short8v a1 = *(const short8v*)&pS[swe(w * 32 + 16 + lr, kb)];
        #pragma unroll
        for (int ni = 0; ni < 8; ++ni) {
            short8v bf = *(const short8v*)&w1S[swe(ni * 16 + lr, kb)];
            acc[0][ni] = __builtin_amdgcn_mfma_f32_16x16x32_bf16(a0, bf, acc[0][ni], 0, 0, 0);
            acc[1][ni] = __builtin_amdgcn_mfma_f32_16x16x32_bf16(a1, bf, acc[1][ni], 0, 0, 0);
        }
    }
    #pragma unroll
    for (int mi = 0; mi < 2; ++mi)
        #pragma unroll
        for (int ni = 0; ni < 8; ++ni) {
            int n = ni * 16 + lr;
            float bv = b1S[n];
            #pragma unroll
            for (int r = 0; r < 4; ++r) {
                int m = w * 32 + mi * 16 + lg * 4 + r;
                hS[swe(m, n)] = f2bf(fmaxf(acc[mi][ni][r] + bv, 0.f));
            }
        }

    f32x4 acc2[2][2];
    #pragma unroll
    for (int mi = 0; mi < 2; ++mi)
        #pragma unroll
        for (int ni = 0; ni < 2; ++ni)
            acc2[mi][ni] = (f32x4){0.f, 0.f, 0.f, 0.f};

    #pragma unroll
    for (int kh = 0; kh < 4; ++kh) {
        int kb = kh * 32 + lg * 8;
        short8v a0 = *(const short8v*)&hS[swe(w * 32 + lr, kb)];
        short8v a1 = *(const short8v*)&hS[swe(w * 32 + 16 + lr, kb)];
        #pragma unroll
        for (int ni = 0; ni < 2; ++ni) {
            short8v bf = *(const short8v*)&w2S[swe(ni * 16 + lr, kb)];
            acc2[0][ni] = __builtin_amdgcn_mfma_f32_16x16x32_bf16(a0, bf, acc2[0][ni], 0, 0, 0);
            acc2[1][ni] = __builtin_amdgcn_mfma_f32_16x16x32_bf16(a1, bf, acc2[1][ni], 0, 0, 0);
        }
    }

    #pragma unroll
    for (int mi = 0; mi < 2; ++mi)
        #pragma unroll
        for (int r = 0; r < 4; ++r) {
            int m = w * 32 + mi * 16 + lg * 4 + r;
            size_t R = (size_t)blockIdx.x * 128 + m;
            float mean = acc2[mi][0][r] + b2S[lr];
            float lv   = acc2[mi][1][r] + b2S[16 + lr];
            float z = noise[R * 16 + lr] * expf(0.5f * lv) + mean;
            nli[R * 16 + lr] = z;
            nli_bf[R * 16 + lr] = f2bf(z);
        }
}

// ================= little_decode via MFMA (unchanged, verified) =============
__global__ __launch_bounds__(256) void k_little_decode_mfma(
    const float* __restrict__ latent,
    const float* __restrict__ w1,
    const float* __restrict__ b1,
    const float* __restrict__ w2,
    const float* __restrict__ b2,
    float* __restrict__ img)
{
    __shared__ __align__(16) unsigned short w1S[128 * 64];
    __shared__ __align__(16) unsigned short hS[128 * 128];
    __shared__ __align__(16) unsigned short w2S[80 * 128];
    __shared__ float b1S[128];
    __shared__ float b2S[80];

    int t = threadIdx.x;

    {
        uint4 z4 = make_uint4(0, 0, 0, 0);
        #pragma unroll
        for (int i = 0; i < 4; ++i)
            *(uint4*)&w1S[(i * 256 + t) * 8] = z4;
        #pragma unroll
        for (int i = 0; i < 5; ++i)
            *(uint4*)&w2S[(i * 256 + t) * 8] = z4;
    }
    __syncthreads();

    {
        int k = t >> 4;
        int n0 = (t & 15) * 8;
        float4 a0 = *(const float4*)(w1 + k * 128 + n0);
        float4 a1 = *(const float4*)(w1 + k * 128 + n0 + 4);
        w1S[swe64(n0 + 0, k)] = f2bf(a0.x);
        w1S[swe64(n0 + 1, k)] = f2bf(a0.y);
        w1S[swe64(n0 + 2, k)] = f2bf(a0.z);
        w1S[swe64(n0 + 3, k)] = f2bf(a0.w);
        w1S[swe64(n0 + 4, k)] = f2bf(a1.x);
        w1S[swe64(n0 + 5, k)] = f2bf(a1.y);
        w1S[swe64(n0 + 6, k)] = f2bf(a1.z);
        w1S[swe64(n0 + 7, k)] = f2bf(a1.w);
    }
    {
        int k = t >> 1;
        int half = t & 1;
        int n0 = half ? 38 : 0, n1 = half ? 75 : 38;
        for (int n = n0; n < n1; ++n)
            w2S[swe(n, k)] = f2bf(w2[k * 75 + n]);
    }
    if (t < 128) b1S[t] = b1[t];
    if (t < 80)  b2S[t] = (t < 75) ? b2[t] : 0.f;
    __syncthreads();

    int w = t >> 6, lane = t & 63, lr = lane & 15, lg = lane >> 4;

    f32x4 acc[2][8];
    #pragma unroll
    for (int mi = 0; mi < 2; ++mi)
        #pragma unroll
        for (int ni = 0; ni < 8; ++ni)
            acc[mi][ni] = (f32x4){0.f, 0.f, 0.f, 0.f};

    short8v af[2];
    #pragma unroll
    for (int mi = 0; mi < 2; ++mi) {
        int m = w * 32 + mi * 16 + lr;
        int R = blockIdx.x * 128 + m;
        int b = R / 169, tt = R - 169 * b;
        if (lg < 2) {
            const float* zp = latent + (size_t)b * 7056 + tt * 16 + lg * 8;
            float4 f0 = *(const float4*)(zp);
            float4 f1 = *(const float4*)(zp + 4);
            af[mi][0] = (short)f2bf(f0.x); af[mi][1] = (short)f2bf(f0.y);
            af[mi][2] = (short)f2bf(f0.z); af[mi][3] = (short)f2bf(f0.w);
            af[mi][4] = (short)f2bf(f1.x); af[mi][5] = (short)f2bf(f1.y);
            af[mi][6] = (short)f2bf(f1.z); af[mi][7] = (short)f2bf(f1.w);
        } else {
            af[mi] = (short8v){0,0,0,0,0,0,0,0};
        }
    }
    {
        int kb = lg * 8;
        #pragma unroll
        for (int ni = 0; ni < 8; ++ni) {
            short8v bf = *(const short8v*)&w1S[swe64(ni * 16 + lr, kb)];
            acc[0][ni] = __builtin_amdgcn_mfma_f32_16x16x32_bf16(af[0], bf, acc[0][ni], 0, 0, 0);
            acc[1][ni] = __builtin_amdgcn_mfma_f32_16x16x32_bf16(af[1], bf, acc[1][ni], 0, 0, 0);
        }
    }
    #pragma unroll
    for (int mi = 0; mi < 2; ++mi)
        #pragma unroll
        for (int ni = 0; ni < 8; ++ni) {
            int n = ni * 16 + lr;
            float bv = b1S[n];
            #pragma unroll
            for (int r = 0; r < 4; ++r) {
                int m = w * 32 + mi * 16 + lg * 4 + r;
                hS[swe(m, n)] = f2bf(fmaxf(acc[mi][ni][r] + bv, 0.f));
            }
        }

    f32x4 acc2[2][5];
    #pragma unroll
    for (int mi = 0; mi < 2; ++mi)
        #pragma unroll
        for (int ni = 0; ni < 5; ++ni)
            acc2[mi][ni] = (f32x4){0.f, 0.f, 0.f, 0.f};

    #pragma unroll
    for (int kh = 0; kh < 4; ++kh) {
        int kb = kh * 32 + lg * 8;
        short8v a0 = *(const short8v*)&hS[swe(w * 32 + lr, kb)];
        short8v a1 = *(const short8v*)&hS[swe(w * 32 + 16 + lr, kb)];
        #pragma unroll
        for (int ni = 0; ni < 5; ++ni) {
            short8v bf = *(const short8v*)&w2S[swe(ni * 16 + lr, kb)];
            acc2[0][ni] = __builtin_amdgcn_mfma_f32_16x16x32_bf16(a0, bf, acc2[0][ni], 0, 0, 0);
            acc2[1][ni] = __builtin_amdgcn_mfma_f32_16x16x32_bf16(a1, bf, acc2[1][ni], 0, 0, 0);
        }
    }

    #pragma unroll
    for (int mi = 0; mi < 2; ++mi)
        #pragma unroll
        for (int r = 0; r < 4; ++r) {
            int m = w * 32 + mi * 16 + lg * 4 + r;
            int R = blockIdx.x * 128 + m;
            int b = R / 169, tt = R - 169 * b;
            int ti = tt / 13, tj = tt - 13 * ti;
            #pragma unroll
            for (int ni = 0; ni < 5; ++ni) {
                int col = ni * 16 + lr;
                if (col < 75) {
                    float a = acc2[mi][ni][r] + b2S[col];
                    float o = 1.f / (1.f + expf(-a));
                    int c = col / 25, o25 = col - 25 * c;
                    int ph = o25 / 5, pw = o25 - 5 * ph;
                    int y = ti * 5 + ph, xx = tj * 5 + pw;
                    if (y < 64 && xx < 64)
                        img[(((size_t)b * 3 + c) * 64 + y) * 64 + xx] = o;
                }
            }
        }
}

// ============ split-K bf16 MFMA GEMM v2: register-double-buffered ===========
// A: 256 x K bf16. W: K x N f32. C: 256 x N f32 PRE-ZEROED, atomic-accum.
// Grid: (N/64, 2 m-halves, S k-chunks). Block 256 thr = 4 waves; BM=128,
// wave w owns rows [w*32, +32). Reg dbuf (issue-early/write-late, T14).
__global__ __launch_bounds__(256, 3) void k_gemm_splitk(
    const unsigned short* __restrict__ A,
    const float* __restrict__ W,
    float* __restrict__ C,
    int N, int K, int baseSteps)
{
    __shared__ __align__(16) unsigned short As[128 * 64];  // 16 KB
    __shared__ __align__(16) unsigned short Ws[64 * 64];   //  8 KB

    int t = threadIdx.x;
    int bn = blockIdx.x * 64;
    int m0 = blockIdx.y * 128;
    int totalSteps = (K + 63) >> 6;
    int step0 = blockIdx.z * baseSteps;
    int nSteps = totalSteps - step0;
    if (nSteps > baseSteps) nSteps = baseSteps;
    if (nSteps <= 0) return;

    const bool nfull = (bn + 64 <= N);

    int w = t >> 6, lane = t & 63, lr = lane & 15, lg = lane >> 4;
    int arow = t >> 1;                 // 0..127
    int ahalf = (t & 1) * 32;          // ushort offset within row
    int bu = t & 15, bg = t >> 4;      // W: cols 4bu..+3, k-rows 4bg..+3
    int nc = bn + 4 * bu;

    const unsigned short* Arow = A + (size_t)(m0 + arow) * K + ahalf;

    uint4  aPa[4], aPb[4];
    float4 wPa[4], wPb[4];

    f32x4 acc[2][4];
    #pragma unroll
    for (int i = 0; i < 2; ++i)
        #pragma unroll
        for (int j = 0; j < 4; ++j)
            acc[i][j] = (f32x4){0.f, 0.f, 0.f, 0.f};

    #define LOAD_T(AP, WP, stepIdx)                                           \
    do {                                                                      \
        int kk0 = (stepIdx) << 6;                                             \
        if ((kk0 + 64 <= K) && nfull) {                                       \
            const uint4* ap = (const uint4*)(Arow + kk0);                     \
            _Pragma("unroll")                                                 \
            for (int u = 0; u < 4; ++u) AP[u] = ap[u];                        \
            const float* wp = W + (size_t)(kk0 + bg * 4) * N + nc;            \
            _Pragma("unroll")                                                 \
            for (int jj = 0; jj < 4; ++jj)                                    \
                WP[jj] = *(const float4*)(wp + (size_t)jj * N);               \
        } else {                                                              \
            _Pragma("unroll")                                                 \
            for (int u = 0; u < 4; ++u) {                                     \
                int ak = kk0 + ahalf + u * 8;                                 \
                if (ak < K) AP[u] = *(const uint4*)(Arow + kk0 + u * 8);      \
                else        AP[u] = make_uint4(0, 0, 0, 0);                   \
            }                                                                 \
            _Pragma("unroll")                                                 \
            for (int jj = 0; jj < 4; ++jj) {                                  \
                int kr = kk0 + bg * 4 + jj;                                   \
                float4 tmp = {0.f, 0.f, 0.f, 0.f};                            \
                if (kr < K) {                                                 \
                    const float* wp = W + (size_t)kr * N;                     \
                    if (nfull) tmp = *(const float4*)(wp + nc);               \
                    else {                                                    \
                        tmp.x = (nc + 0 < N) ? wp[nc + 0] : 0.f;              \
                        tmp.y = (nc + 1 < N) ? wp[nc + 1] : 0.f;              \
                        tmp.z = (nc + 2 < N) ? wp[nc + 2] : 0.f;              \
                        tmp.w = (nc + 3 < N) ? wp[nc + 3] : 0.f;              \
                    }                                                         \
                }                                                             \
                WP[jj] = tmp;                                                 \
            }                                                                 \
        }                                                                     \
    } while (0)

    #define STORE_T(AP, WP)                                                   \
    do {                                                                      \
        _Pragma("unroll")                                                     \
        for (int u = 0; u < 4; ++u)                                           \
            *(uint4*)&As[swe64(arow, ahalf + u * 8)] = AP[u];                 \
        _Pragma("unroll")                                                     \
        for (int c = 0; c < 4; ++c) {                                         \
            int n = 4 * bu + c;                                               \
            float e0 = (c == 0) ? WP[0].x : (c == 1) ? WP[0].y                \
                     : (c == 2) ? WP[0].z : WP[0].w;                          \
            float e1 = (c == 0) ? WP[1].x : (c == 1) ? WP[1].y                \
                     : (c == 2) ? WP[1].z : WP[1].w;                          \
            float e2 = (c == 0) ? WP[2].x : (c == 1) ? WP[2].y                \
                     : (c == 2) ? WP[2].z : WP[2].w;                          \
            float e3 = (c == 0) ? WP[3].x : (c == 1) ? WP[3].y                \
                     : (c == 2) ? WP[3].z : WP[3].w;                          \
            u16x4 pk;                                                         \
            pk.x = f2bf(e0); pk.y = f2bf(e1);                                 \
            pk.z = f2bf(e2); pk.w = f2bf(e3);                                 \
            *(u16x4*)&Ws[swe64(n, 4 * bg)] = pk;                              \
        }                                                                     \
    } while (0)

    #define MFMA_T                                                            \
    do {                                                                      \
        _Pragma("unroll")                                                     \
        for (int kk = 0; kk < 64; kk += 32) {                                 \
            short8v afr[2], bfr[4];                                           \
            _Pragma("unroll")                                                 \
            for (int mi = 0; mi < 2; ++mi)                                    \
                afr[mi] = *(const short8v*)&As[swe64(w * 32 + mi * 16 + lr,   \
                                                    kk + lg * 8)];            \
            _Pragma("unroll")                                                 \
            for (int ni = 0; ni < 4; ++ni)                                    \
                bfr[ni] = *(const short8v*)&Ws[swe64(ni * 16 + lr,            \
                                                    kk + lg * 8)];            \
            _Pragma("unroll")                                                 \
            for (int mi = 0; mi < 2; ++mi)                                    \
                _Pragma("unroll")                                             \
                for (int ni = 0; ni < 4; ++ni)                                \
                    acc[mi][ni] = __builtin_amdgcn_mfma_f32_16x16x32_bf16(    \
                        afr[mi], bfr[ni], acc[mi][ni], 0, 0, 0);              \
        }                                                                     \
    } while (0)

    LOAD_T(aPa, wPa, step0);

    for (int ti = 0; ti < nSteps; ti += 2) {
        if (ti + 1 < nSteps) LOAD_T(aPb, wPb, step0 + ti + 1);  // issue early
        __syncthreads();            // prev MFMA consumers done
        STORE_T(aPa, wPa);          // waits only on aPa/wPa loads
        __syncthreads();
        MFMA_T;
        if (ti + 1 < nSteps) {
            if (ti + 2 < nSteps) LOAD_T(aPa, wPa, step0 + ti + 2);
            __syncthreads();
            STORE_T(aPb, wPb);
            __syncthreads();
            MFMA_T;
        }
    }
    #undef LOAD_T
    #undef STORE_T
    #undef MFMA_T

    // atomic-add epilogue
    #pragma unroll
    for (int ni = 0; ni < 4; ++ni) {
        int col = bn + ni * 16 + lr;
        if (col < N) {
            #pragma unroll
            for (int mi = 0; mi < 2; ++mi) {
                int row = m0 + w * 32 + mi * 16 + lg * 4;
                #pragma unroll
                for (int r = 0; r < 4; ++r)
                    __hip_atomic_fetch_add(&C[(size_t)(row + r) * N + col],
                                           acc[mi][ni][r],
                                           __ATOMIC_RELAXED,
                                           __HIP_MEMORY_SCOPE_AGENT);
            }
        }
    }
}

// ---------- stats partial: applies relu(h_raw + enc_b1) on load ------------
__global__ __launch_bounds__(256) void k_stats_partial(
    const float* __restrict__ h_e,    // RAW (no bias/relu)
    const float* __restrict__ enc_b1, // (4096)
    const float* __restrict__ w2,
    float* __restrict__ psum)
{
    __shared__ float hs[16][256];
    int mg = blockIdx.x >> 4;
    int ks = blockIdx.x & 15;
    int t = threadIdx.x;

    for (int i = t; i < 16 * 256; i += 256) {
        int mm = i >> 8, kk = i & 255;
        hs[mm][kk] = fmaxf(
            h_e[(size_t)(mg * 16 + mm) * 4096 + ks * 256 + kk] + enc_b1[ks * 256 + kk],
            0.f);
    }
    __syncthreads();

    int n = t & 127, mh = t >> 7;
    float acc[8] = {0.f,0.f,0.f,0.f,0.f,0.f,0.f,0.f};
    const float* w2p = w2 + (size_t)(ks * 256) * 128 + n;
    for (int k = 0; k < 256; ++k) {
        float wv = w2p[(size_t)k * 128];
        #pragma unroll
        for (int mm = 0; mm < 8; ++mm)
            acc[mm] += hs[mh * 8 + mm][k] * wv;
    }
    #pragma unroll
    for (int mm = 0; mm < 8; ++mm) {
        int m = mg * 16 + mh * 8 + mm;
        psum[((size_t)m * 16 + ks) * 128 + n] = acc[mm];
    }
}

// ---------- mid2 (unchanged) ----------
__global__ __launch_bounds__(256) void k_mid2(
    const float* __restrict__ psum,
    const float* __restrict__ enc_b2,
    const float* __restrict__ noise_z,
    const float* __restrict__ dec_w1, const float* __restrict__ dec_b1,
    const float* __restrict__ dec_w2, const float* __restrict__ dec_b2,
    float* __restrict__ mean_out, float* __restrict__ logvar_out,
    unsigned short* __restrict__ h2bf)
{
    __shared__ float st[128];
    __shared__ float z_s[64];
    __shared__ float h1_s[32];

    int m = blockIdx.x >> 2, ch = blockIdx.x & 3;
    int t = threadIdx.x;

    if (t < 128) {
        float a = enc_b2[t];
        #pragma unroll 4
        for (int ks = 0; ks < 16; ++ks)
            a += psum[((size_t)m * 16 + ks) * 128 + t];
        st[t] = fmaxf(a, 0.f);
    }
    __syncthreads();

    if (t < 64) {
        float mean = st[t], lv = st[t + 64];
        if (ch == 0) {
            mean_out[(size_t)m * 64 + t]   = mean;
            logvar_out[(size_t)m * 64 + t] = lv;
        }
        z_s[t] = noise_z[(size_t)m * 64 + t] * expf(0.5f * lv) + mean;
    }
    __syncthreads();

    if (t < 32) {
        float a = dec_b1[t];
        #pragma unroll 8
        for (int k = 0; k < 64; ++k) a += z_s[k] * dec_w1[k * 32 + t];
        h1_s[t] = fmaxf(a, 0.f);
    }
    __syncthreads();

    #pragma unroll
    for (int j = 0; j < 4; ++j) {
        int nn = ch * 1024 + j * 256 + t;
        float a = dec_b2[nn];
        #pragma unroll 8
        for (int k = 0; k < 32; ++k)
            a += h1_s[k] * dec_w2[(size_t)k * 4096 + nn];
        h2bf[(size_t)m * 4096 + nn] = f2bf(fmaxf(a, 0.f));
    }
}

// ---------- latent epilogue: latent = relu(raw + dec_b3[col]) in place -----
__global__ __launch_bounds__(256) void k_bias_relu(
    float* __restrict__ buf, const float* __restrict__ bias)
{
    int idx = blockIdx.x * 256 + threadIdx.x;
    #pragma unroll
    for (int j = 0; j < 4; ++j) {
        int f = idx + j * 112896;
        int col4 = f % 1764;
        float4 v = ((float4*)buf)[f];
        float4 b = *(const float4*)(bias + col4 * 4);
        v.x = fmaxf(v.x + b.x, 0.f);
        v.y = fmaxf(v.y + b.y, 0.f);
        v.z = fmaxf(v.z + b.z, 0.f);
        v.w = fmaxf(v.w + b.w, 0.f);
        ((float4*)buf)[f] = v;
    }
}

extern "C" void kernel_launch(void* const* d_in, const int* in_sizes, int n_in,
                              void* d_out, int out_size, void* d_ws, size_t ws_size,
                              hipStream_t stream) {
    const float* x            = (const float*)d_in[0];
    const float* noise_little = (const float*)d_in[1];
    const float* noise_z      = (const float*)d_in[2];
    const float* le_w1        = (const float*)d_in[3];
    const float* le_b1        = (const float*)d_in[4];
    const float* le_w2        = (const float*)d_in[5];
    const float* le_b2        = (const float*)d_in[6];
    const float* ld_w1        = (const float*)d_in[7];
    const float* ld_b1        = (const float*)d_in[8];
    const float* ld_w2        = (const float*)d_in[9];
    const float* ld_b2        = (const float*)d_in[10];
    const float* enc_w1       = (const float*)d_in[11];
    const float* enc_b1       = (const float*)d_in[12];
    const float* enc_w2       = (const float*)d_in[13];
    const float* enc_b2       = (const float*)d_in[14];
    const float* dec_w1       = (const float*)d_in[15];
    const float* dec_b1       = (const float*)d_in[16];
    const float* dec_w2       = (const float*)d_in[17];
    const float* dec_b2       = (const float*)d_in[18];
    const float* dec_w3       = (const float*)d_in[19];
    const float* dec_b3       = (const float*)d_in[20];

    float* out = (float*)d_out;
    float* latent = out;                       // 1,806,336
    float* mean   = latent + 1806336;          // 16,384
    float* logvar = mean + 16384;              // 16,384
    float* nli    = logvar + 16384;            // 1,806,336
    float* img    = nli + 1806336;             // 3,145,728

    float* h_e = latent;   // raw GEMM1 output parked here; wiped before GEMM2

    unsigned short* nli_bf = (unsigned short*)d_ws;                       // 3,612,672 B
    float* psum = (float*)((char*)d_ws + 3612672);                        // 2,097,152 B
    unsigned short* h2bf = (unsigned short*)((char*)d_ws + 5709824);      // 2,097,152 B

    // 0) zero h_e accumulation region (4 MB)
    hipMemsetAsync(h_e, 0, (size_t)256 * 4096 * 4, stream);

    // 1) patches + little_encode + reparam (MFMA)
    k_little_encode_mfma<<<882, 256, 0, stream>>>(
        x, noise_little, le_w1, le_b1, le_w2, le_b2, nli, nli_bf);

    // 2) h_e_raw += nli @ enc_w1   [256x7056 @ 7056x4096]  S=8, M-split 2
    k_gemm_splitk<<<dim3(64, 2, 8), 256, 0, stream>>>(
        nli_bf, enc_w1, h_e, 4096, 7056, 14);

    // 3a) psum partials (bias+relu fused on h_e load)
    k_stats_partial<<<256, 256, 0, stream>>>(h_e, enc_b1, enc_w2, psum);

    // 3b) reduce + reparam + dec1 + dec2
    k_mid2<<<1024, 256, 0, stream>>>(
        psum, enc_b2, noise_z, dec_w1, dec_b1, dec_w2, dec_b2,
        mean, logvar, h2bf);

    // 4) zero latent accumulation region (7.2 MB), then split-K GEMM
    hipMemsetAsync(latent, 0, (size_t)1806336 * 4, stream);
    k_gemm_splitk<<<dim3(111, 2, 8), 256, 0, stream>>>(
        h2bf, dec_w3, latent, 7056, 4096, 8);

    // 4b) latent = relu(latent_raw + dec_b3)
    k_bias_relu<<<441, 256, 0, stream>>>(latent, dec_b3);

    // 5) little_decode + canvas (MFMA)
    k_little_decode_mfma<<<338, 256, 0, stream>>>(
        latent, ld_w1, ld_b1, ld_w2, ld_b2, img);
}

// Round 7
// 233.345 us; speedup vs baseline: 8.0100x; 1.0214x over previous
//
#include <hip/hip_runtime.h>
#include <math.h>

#define EPSF 1e-6f

typedef __attribute__((ext_vector_type(8))) short short8v;
typedef __attribute__((ext_vector_type(4))) float f32x4;
typedef __attribute__((ext_vector_type(4))) unsigned short u16x4;

__device__ __forceinline__ unsigned short f2bf(float f) {
    union { float f; unsigned u; } v; v.f = f;
    return (unsigned short)((v.u + 0x7FFFu + ((v.u >> 16) & 1u)) >> 16);
}
// XOR swizzle for [row][128-ushort] LDS tiles (16B granularity)
__device__ __forceinline__ int swe(int row, int k) {
    return (row << 7) + (k ^ ((row & 7) << 3));
}
// XOR swizzle for [row][64-ushort] LDS tiles
__device__ __forceinline__ int swe64(int row, int k) {
    return (row << 6) + (k ^ ((row & 7) << 3));
}

// ================= little_encode via MFMA (unchanged, verified) =============
__global__ __launch_bounds__(256) void k_little_encode_mfma(
    const float* __restrict__ x,
    const float* __restrict__ noise,
    const float* __restrict__ w1,
    const float* __restrict__ b1,
    const float* __restrict__ w2,
    const float* __restrict__ b2,
    float* __restrict__ nli,
    unsigned short* __restrict__ nli_bf)
{
    __shared__ __align__(16) unsigned short pS[128 * 128];
    __shared__ __align__(16) unsigned short w1S[128 * 128];
    __shared__ __align__(16) unsigned short hS[128 * 128];
    __shared__ __align__(16) unsigned short w2S[32 * 128];
    __shared__ float b1S[128];
    __shared__ float b2S[32];
    __shared__ float sums[128][4];

    int t = threadIdx.x;

    {
        uint4 z4 = make_uint4(0, 0, 0, 0);
        #pragma unroll
        for (int i = 0; i < 8; ++i) {
            *(uint4*)&pS[(i * 256 + t) * 8]  = z4;
            *(uint4*)&w1S[(i * 256 + t) * 8] = z4;
        }
    }
    __syncthreads();

    for (int k = (t >> 4); k < 75; k += 16) {
        int n0 = (t & 15) * 8;
        float4 a0 = *(const float4*)(w1 + k * 128 + n0);
        float4 a1 = *(const float4*)(w1 + k * 128 + n0 + 4);
        w1S[swe(n0 + 0, k)] = f2bf(a0.x);
        w1S[swe(n0 + 1, k)] = f2bf(a0.y);
        w1S[swe(n0 + 2, k)] = f2bf(a0.z);
        w1S[swe(n0 + 3, k)] = f2bf(a0.w);
        w1S[swe(n0 + 4, k)] = f2bf(a1.x);
        w1S[swe(n0 + 5, k)] = f2bf(a1.y);
        w1S[swe(n0 + 6, k)] = f2bf(a1.z);
        w1S[swe(n0 + 7, k)] = f2bf(a1.w);
    }
    for (int k = (t >> 3); k < 128; k += 32) {
        int n0 = (t & 7) * 4;
        float4 a = *(const float4*)(w2 + k * 32 + n0);
        w2S[swe(n0 + 0, k)] = f2bf(a.x);
        w2S[swe(n0 + 1, k)] = f2bf(a.y);
        w2S[swe(n0 + 2, k)] = f2bf(a.z);
        w2S[swe(n0 + 3, k)] = f2bf(a.w);
    }
    if (t < 128) b1S[t] = b1[t];
    if (t < 32)  b2S[t] = b2[t];

    int row  = t & 127;
    int half = t >> 7;
    int R0 = blockIdx.x * 128 + row;
    int bb = R0 / 441;
    int p  = R0 - bb * 441;
    int pi = p / 21, pj = p - pi * 21;
    const float* xb = x + (size_t)bb * 3 * 63 * 63;

    float v[38];
    {
        float sA = 0.f, sB = 0.f;
        if (half == 0) {
            #pragma unroll
            for (int i = 0; i < 38; ++i) {
                const int k = i;
                const int c = k / 25, o = k % 25, ph = o / 5, pw = o % 5;
                int y = pi * 3 + ph - 1, xx = pj * 3 + pw - 1;
                float val = 0.f;
                if ((unsigned)y < 63u && (unsigned)xx < 63u)
                    val = xb[(c * 63 + y) * 63 + xx];
                v[i] = val;
                if (k < 25) sA += val; else sB += val;
            }
        } else {
            #pragma unroll
            for (int i = 0; i < 37; ++i) {
                const int k = 38 + i;
                const int c = k / 25, o = k % 25, ph = o / 5, pw = o % 5;
                int y = pi * 3 + ph - 1, xx = pj * 3 + pw - 1;
                float val = 0.f;
                if ((unsigned)y < 63u && (unsigned)xx < 63u)
                    val = xb[(c * 63 + y) * 63 + xx];
                v[i] = val;
                if (k < 50) sA += val; else sB += val;
            }
        }
        sums[row][half * 2 + 0] = sA;
        sums[row][half * 2 + 1] = sB;
    }
    __syncthreads();
    {
        float c0 = sums[row][0];
        float c1 = sums[row][1] + sums[row][2];
        float c2 = sums[row][3];
        if (half == 0) {
            #pragma unroll
            for (int i = 0; i < 38; ++i) {
                const int k = i;
                float cs = (k < 25) ? c0 : c1;
                pS[swe(row, k)] = f2bf(v[i] + EPSF * cs);
            }
        } else {
            #pragma unroll
            for (int i = 0; i < 37; ++i) {
                const int k = 38 + i;
                float cs = (k < 50) ? c1 : c2;
                pS[swe(row, k)] = f2bf(v[i] + EPSF * cs);
            }
        }
    }
    __syncthreads();

    int w = t >> 6, lane = t & 63, lr = lane & 15, lg = lane >> 4;

    f32x4 acc[2][8];
    #pragma unroll
    for (int mi = 0; mi < 2; ++mi)
        #pragma unroll
        for (int ni = 0; ni < 8; ++ni)
            acc[mi][ni] = (f32x4){0.f, 0.f, 0.f, 0.f};

    #pragma unroll
    for (int ks = 0; ks < 3; ++ks) {
        int kb = ks * 32 + lg * 8;
        short8v a0 = *(const short8v*)&pS[swe(w * 32 + lr, kb)];
        short8v a1 = *(const short8v*)&pS[swe(w * 32 + 16 + lr, kb)];
        #pragma unroll
        for (int ni = 0; ni < 8; ++ni) {
            short8v bf = *(const short8v*)&w1S[swe(ni * 16 + lr, kb)];
            acc[0][ni] = __builtin_amdgcn_mfma_f32_16x16x32_bf16(a0, bf, acc[0][ni], 0, 0, 0);
            acc[1][ni] = __builtin_amdgcn_mfma_f32_16x16x32_bf16(a1, bf, acc[1][ni], 0, 0, 0);
        }
    }
    #pragma unroll
    for (int mi = 0; mi < 2; ++mi)
        #pragma unroll
        for (int ni = 0; ni < 8; ++ni) {
            int n = ni * 16 + lr;
            float bv = b1S[n];
            #pragma unroll
            for (int r = 0; r < 4; ++r) {
                int m = w * 32 + mi * 16 + lg * 4 + r;
                hS[swe(m, n)] = f2bf(fmaxf(acc[mi][ni][r] + bv, 0.f));
            }
        }

    f32x4 acc2[2][2];
    #pragma unroll
    for (int mi = 0; mi < 2; ++mi)
        #pragma unroll
        for (int ni = 0; ni < 2; ++ni)
            acc2[mi][ni] = (f32x4){0.f, 0.f, 0.f, 0.f};

    #pragma unroll
    for (int kh = 0; kh < 4; ++kh) {
        int kb = kh * 32 + lg * 8;
        short8v a0 = *(const short8v*)&hS[swe(w * 32 + lr, kb)];
        short8v a1 = *(const short8v*)&hS[swe(w * 32 + 16 + lr, kb)];
        #pragma unroll
        for (int ni = 0; ni < 2; ++ni) {
            short8v bf = *(const short8v*)&w2S[swe(ni * 16 + lr, kb)];
            acc2[0][ni] = __builtin_amdgcn_mfma_f32_16x16x32_bf16(a0, bf, acc2[0][ni], 0, 0, 0);
            acc2[1][ni] = __builtin_amdgcn_mfma_f32_16x16x32_bf16(a1, bf, acc2[1][ni], 0, 0, 0);
        }
    }

    #pragma unroll
    for (int mi = 0; mi < 2; ++mi)
        #pragma unroll
        for (int r = 0; r < 4; ++r) {
            int m = w * 32 + mi * 16 + lg * 4 + r;
            size_t R = (size_t)blockIdx.x * 128 + m;
            float mean = acc2[mi][0][r] + b2S[lr];
            float lv   = acc2[mi][1][r] + b2S[16 + lr];
            float z = noise[R * 16 + lr] * expf(0.5f * lv) + mean;
            nli[R * 16 + lr] = z;
            nli_bf[R * 16 + lr] = f2bf(z);
        }
}

// ================= little_decode via MFMA (unchanged, verified) =============
__global__ __launch_bounds__(256) void k_little_decode_mfma(
    const float* __restrict__ latent,
    const float* __restrict__ w1,
    const float* __restrict__ b1,
    const float* __restrict__ w2,
    const float* __restrict__ b2,
    float* __restrict__ img)
{
    __shared__ __align__(16) unsigned short w1S[128 * 64];
    __shared__ __align__(16) unsigned short hS[128 * 128];
    __shared__ __align__(16) unsigned short w2S[80 * 128];
    __shared__ float b1S[128];
    __shared__ float b2S[80];

    int t = threadIdx.x;

    {
        uint4 z4 = make_uint4(0, 0, 0, 0);
        #pragma unroll
        for (int i = 0; i < 4; ++i)
            *(uint4*)&w1S[(i * 256 + t) * 8] = z4;
        #pragma unroll
        for (int i = 0; i < 5; ++i)
            *(uint4*)&w2S[(i * 256 + t) * 8] = z4;
    }
    __syncthreads();

    {
        int k = t >> 4;
        int n0 = (t & 15) * 8;
        float4 a0 = *(const float4*)(w1 + k * 128 + n0);
        float4 a1 = *(const float4*)(w1 + k * 128 + n0 + 4);
        w1S[swe64(n0 + 0, k)] = f2bf(a0.x);
        w1S[swe64(n0 + 1, k)] = f2bf(a0.y);
        w1S[swe64(n0 + 2, k)] = f2bf(a0.z);
        w1S[swe64(n0 + 3, k)] = f2bf(a0.w);
        w1S[swe64(n0 + 4, k)] = f2bf(a1.x);
        w1S[swe64(n0 + 5, k)] = f2bf(a1.y);
        w1S[swe64(n0 + 6, k)] = f2bf(a1.z);
        w1S[swe64(n0 + 7, k)] = f2bf(a1.w);
    }
    {
        int k = t >> 1;
        int half = t & 1;
        int n0 = half ? 38 : 0, n1 = half ? 75 : 38;
        for (int n = n0; n < n1; ++n)
            w2S[swe(n, k)] = f2bf(w2[k * 75 + n]);
    }
    if (t < 128) b1S[t] = b1[t];
    if (t < 80)  b2S[t] = (t < 75) ? b2[t] : 0.f;
    __syncthreads();

    int w = t >> 6, lane = t & 63, lr = lane & 15, lg = lane >> 4;

    f32x4 acc[2][8];
    #pragma unroll
    for (int mi = 0; mi < 2; ++mi)
        #pragma unroll
        for (int ni = 0; ni < 8; ++ni)
            acc[mi][ni] = (f32x4){0.f, 0.f, 0.f, 0.f};

    short8v af[2];
    #pragma unroll
    for (int mi = 0; mi < 2; ++mi) {
        int m = w * 32 + mi * 16 + lr;
        int R = blockIdx.x * 128 + m;
        int b = R / 169, tt = R - 169 * b;
        if (lg < 2) {
            const float* zp = latent + (size_t)b * 7056 + tt * 16 + lg * 8;
            float4 f0 = *(const float4*)(zp);
            float4 f1 = *(const float4*)(zp + 4);
            af[mi][0] = (short)f2bf(f0.x); af[mi][1] = (short)f2bf(f0.y);
            af[mi][2] = (short)f2bf(f0.z); af[mi][3] = (short)f2bf(f0.w);
            af[mi][4] = (short)f2bf(f1.x); af[mi][5] = (short)f2bf(f1.y);
            af[mi][6] = (short)f2bf(f1.z); af[mi][7] = (short)f2bf(f1.w);
        } else {
            af[mi] = (short8v){0,0,0,0,0,0,0,0};
        }
    }
    {
        int kb = lg * 8;
        #pragma unroll
        for (int ni = 0; ni < 8; ++ni) {
            short8v bf = *(const short8v*)&w1S[swe64(ni * 16 + lr, kb)];
            acc[0][ni] = __builtin_amdgcn_mfma_f32_16x16x32_bf16(af[0], bf, acc[0][ni], 0, 0, 0);
            acc[1][ni] = __builtin_amdgcn_mfma_f32_16x16x32_bf16(af[1], bf, acc[1][ni], 0, 0, 0);
        }
    }
    #pragma unroll
    for (int mi = 0; mi < 2; ++mi)
        #pragma unroll
        for (int ni = 0; ni < 8; ++ni) {
            int n = ni * 16 + lr;
            float bv = b1S[n];
            #pragma unroll
            for (int r = 0; r < 4; ++r) {
                int m = w * 32 + mi * 16 + lg * 4 + r;
                hS[swe(m, n)] = f2bf(fmaxf(acc[mi][ni][r] + bv, 0.f));
            }
        }

    f32x4 acc2[2][5];
    #pragma unroll
    for (int mi = 0; mi < 2; ++mi)
        #pragma unroll
        for (int ni = 0; ni < 5; ++ni)
            acc2[mi][ni] = (f32x4){0.f, 0.f, 0.f, 0.f};

    #pragma unroll
    for (int kh = 0; kh < 4; ++kh) {
        int kb = kh * 32 + lg * 8;
        short8v a0 = *(const short8v*)&hS[swe(w * 32 + lr, kb)];
        short8v a1 = *(const short8v*)&hS[swe(w * 32 + 16 + lr, kb)];
        #pragma unroll
        for (int ni = 0; ni < 5; ++ni) {
            short8v bf = *(const short8v*)&w2S[swe(ni * 16 + lr, kb)];
            acc2[0][ni] = __builtin_amdgcn_mfma_f32_16x16x32_bf16(a0, bf, acc2[0][ni], 0, 0, 0);
            acc2[1][ni] = __builtin_amdgcn_mfma_f32_16x16x32_bf16(a1, bf, acc2[1][ni], 0, 0, 0);
        }
    }

    #pragma unroll
    for (int mi = 0; mi < 2; ++mi)
        #pragma unroll
        for (int r = 0; r < 4; ++r) {
            int m = w * 32 + mi * 16 + lg * 4 + r;
            int R = blockIdx.x * 128 + m;
            int b = R / 169, tt = R - 169 * b;
            int ti = tt / 13, tj = tt - 13 * ti;
            #pragma unroll
            for (int ni = 0; ni < 5; ++ni) {
                int col = ni * 16 + lr;
                if (col < 75) {
                    float a = acc2[mi][ni][r] + b2S[col];
                    float o = 1.f / (1.f + expf(-a));
                    int c = col / 25, o25 = col - 25 * c;
                    int ph = o25 / 5, pw = o25 - 5 * ph;
                    int y = ti * 5 + ph, xx = tj * 5 + pw;
                    if (y < 64 && xx < 64)
                        img[(((size_t)b * 3 + c) * 64 + y) * 64 + xx] = o;
                }
            }
        }
}

// ============ split-K bf16 MFMA GEMM v3 =====================================
// EPI=0: atomic-accumulate into pre-zeroed C (fallback).
// EPI=1: plain stores into per-chunk partials C[z][256][N] (ws path).
// Padded LDS rows (72 ushorts = 144B = 9*16B): row base bank = 4*row mod 32
// -> b128 reads/writes <=2-way (free). No XOR swizzle.
template<int EPI>
__global__ __launch_bounds__(256, 3) void k_gemm_splitk(
    const unsigned short* __restrict__ A,
    const float* __restrict__ W,
    float* __restrict__ C,
    int N, int K, int baseSteps)
{
    __shared__ __align__(16) unsigned short As[128 * 72];  // 18 KB
    __shared__ __align__(16) unsigned short Ws[64 * 72];   //  9 KB

    int t = threadIdx.x;
    int bn = blockIdx.x * 64;
    int m0 = blockIdx.y * 128;
    int totalSteps = (K + 63) >> 6;
    int step0 = blockIdx.z * baseSteps;
    int nSteps = totalSteps - step0;
    if (nSteps > baseSteps) nSteps = baseSteps;
    if (nSteps <= 0) return;

    const bool nfull = (bn + 64 <= N);

    int w = t >> 6, lane = t & 63, lr = lane & 15, lg = lane >> 4;
    int arow = t >> 1;                 // 0..127
    int ahalf = (t & 1) * 32;          // ushort offset within row
    int bu = t & 15, bg = t >> 4;      // W: cols 4bu..+3, k-rows 4bg..+3
    int nc = bn + 4 * bu;

    const unsigned short* Arow = A + (size_t)(m0 + arow) * K + ahalf;

    uint4  aPa[4], aPb[4];
    float4 wPa[4], wPb[4];

    f32x4 acc[2][4];
    #pragma unroll
    for (int i = 0; i < 2; ++i)
        #pragma unroll
        for (int j = 0; j < 4; ++j)
            acc[i][j] = (f32x4){0.f, 0.f, 0.f, 0.f};

    #define LOAD_T(AP, WP, stepIdx)                                           \
    do {                                                                      \
        int kk0 = (stepIdx) << 6;                                             \
        if ((kk0 + 64 <= K) && nfull) {                                       \
            const uint4* ap = (const uint4*)(Arow + kk0);                     \
            _Pragma("unroll")                                                 \
            for (int u = 0; u < 4; ++u) AP[u] = ap[u];                        \
            const float* wp = W + (size_t)(kk0 + bg * 4) * N + nc;            \
            _Pragma("unroll")                                                 \
            for (int jj = 0; jj < 4; ++jj)                                    \
                WP[jj] = *(const float4*)(wp + (size_t)jj * N);               \
        } else {                                                              \
            _Pragma("unroll")                                                 \
            for (int u = 0; u < 4; ++u) {                                     \
                int ak = kk0 + ahalf + u * 8;                                 \
                if (ak < K) AP[u] = *(const uint4*)(Arow + kk0 + u * 8);      \
                else        AP[u] = make_uint4(0, 0, 0, 0);                   \
            }                                                                 \
            _Pragma("unroll")                                                 \
            for (int jj = 0; jj < 4; ++jj) {                                  \
                int kr = kk0 + bg * 4 + jj;                                   \
                float4 tmp = {0.f, 0.f, 0.f, 0.f};                            \
                if (kr < K) {                                                 \
                    const float* wp = W + (size_t)kr * N;                     \
                    if (nfull) tmp = *(const float4*)(wp + nc);               \
                    else {                                                    \
                        tmp.x = (nc + 0 < N) ? wp[nc + 0] : 0.f;              \
                        tmp.y = (nc + 1 < N) ? wp[nc + 1] : 0.f;              \
                        tmp.z = (nc + 2 < N) ? wp[nc + 2] : 0.f;              \
                        tmp.w = (nc + 3 < N) ? wp[nc + 3] : 0.f;              \
                    }                                                         \
                }                                                             \
                WP[jj] = tmp;                                                 \
            }                                                                 \
        }                                                                     \
    } while (0)

    #define STORE_T(AP, WP)                                                   \
    do {                                                                      \
        _Pragma("unroll")                                                     \
        for (int u = 0; u < 4; ++u)                                           \
            *(uint4*)&As[arow * 72 + ahalf + u * 8] = AP[u];                  \
        _Pragma("unroll")                                                     \
        for (int c = 0; c < 4; ++c) {                                         \
            int n = 4 * bu + c;                                               \
            float e0 = (c == 0) ? WP[0].x : (c == 1) ? WP[0].y                \
                     : (c == 2) ? WP[0].z : WP[0].w;                          \
            float e1 = (c == 0) ? WP[1].x : (c == 1) ? WP[1].y                \
                     : (c == 2) ? WP[1].z : WP[1].w;                          \
            float e2 = (c == 0) ? WP[2].x : (c == 1) ? WP[2].y                \
                     : (c == 2) ? WP[2].z : WP[2].w;                          \
            float e3 = (c == 0) ? WP[3].x : (c == 1) ? WP[3].y                \
                     : (c == 2) ? WP[3].z : WP[3].w;                          \
            u16x4 pk;                                                         \
            pk.x = f2bf(e0); pk.y = f2bf(e1);                                 \
            pk.z = f2bf(e2); pk.w = f2bf(e3);                                 \
            *(u16x4*)&Ws[n * 72 + 4 * bg] = pk;                               \
        }                                                                     \
    } while (0)

    #define MFMA_T                                                            \
    do {                                                                      \
        _Pragma("unroll")                                                     \
        for (int kk = 0; kk < 64; kk += 32) {                                 \
            short8v afr[2], bfr[4];                                           \
            _Pragma("unroll")                                                 \
            for (int mi = 0; mi < 2; ++mi)                                    \
                afr[mi] = *(const short8v*)&As[(w * 32 + mi * 16 + lr) * 72   \
                                               + kk + lg * 8];                \
            _Pragma("unroll")                                                 \
            for (int ni = 0; ni < 4; ++ni)                                    \
                bfr[ni] = *(const short8v*)&Ws[(ni * 16 + lr) * 72            \
                                               + kk + lg * 8];                \
            _Pragma("unroll")                                                 \
            for (int mi = 0; mi < 2; ++mi)                                    \
                _Pragma("unroll")                                             \
                for (int ni = 0; ni < 4; ++ni)                                \
                    acc[mi][ni] = __builtin_amdgcn_mfma_f32_16x16x32_bf16(    \
                        afr[mi], bfr[ni], acc[mi][ni], 0, 0, 0);              \
        }                                                                     \
    } while (0)

    LOAD_T(aPa, wPa, step0);

    for (int ti = 0; ti < nSteps; ti += 2) {
        if (ti + 1 < nSteps) LOAD_T(aPb, wPb, step0 + ti + 1);  // issue early
        __syncthreads();
        STORE_T(aPa, wPa);
        __syncthreads();
        MFMA_T;
        if (ti + 1 < nSteps) {
            if (ti + 2 < nSteps) LOAD_T(aPa, wPa, step0 + ti + 2);
            __syncthreads();
            STORE_T(aPb, wPb);
            __syncthreads();
            MFMA_T;
        }
    }
    #undef LOAD_T
    #undef STORE_T
    #undef MFMA_T

    if (EPI == 1) {
        // plain stores into partial buffer C[z][256][N]
        float* Cz = C + (size_t)blockIdx.z * 256 * N;
        #pragma unroll
        for (int ni = 0; ni < 4; ++ni) {
            int col = bn + ni * 16 + lr;
            if (col < N) {
                #pragma unroll
                for (int mi = 0; mi < 2; ++mi) {
                    int row = m0 + w * 32 + mi * 16 + lg * 4;
                    #pragma unroll
                    for (int r = 0; r < 4; ++r)
                        Cz[(size_t)(row + r) * N + col] = acc[mi][ni][r];
                }
            }
        }
    } else {
        #pragma unroll
        for (int ni = 0; ni < 4; ++ni) {
            int col = bn + ni * 16 + lr;
            if (col < N) {
                #pragma unroll
                for (int mi = 0; mi < 2; ++mi) {
                    int row = m0 + w * 32 + mi * 16 + lg * 4;
                    #pragma unroll
                    for (int r = 0; r < 4; ++r)
                        __hip_atomic_fetch_add(&C[(size_t)(row + r) * N + col],
                                               acc[mi][ni][r],
                                               __ATOMIC_RELAXED,
                                               __HIP_MEMORY_SCOPE_AGENT);
                }
            }
        }
    }
}

// ---------- reduce partials + bias + relu (also used S=1 in-place) ---------
__global__ __launch_bounds__(256) void k_reduce_bias_relu(
    const float* __restrict__ parts, const float* __restrict__ bias,
    float* __restrict__ out, int S, int N)
{
    int nF4 = (256 / 4) * N;          // 64*N float4 elems
    int nCol4 = N >> 2;
    size_t strideF4 = (size_t)64 * N; // float4 stride between z-slices
    for (int idx = blockIdx.x * 256 + threadIdx.x; idx < nF4;
         idx += gridDim.x * 256) {
        int col4 = idx % nCol4;
        float4 b = *(const float4*)(bias + col4 * 4);
        float4 a = ((const float4*)parts)[idx];
        for (int z = 1; z < S; ++z) {
            float4 p = ((const float4*)parts)[(size_t)z * strideF4 + idx];
            a.x += p.x; a.y += p.y; a.z += p.z; a.w += p.w;
        }
        a.x = fmaxf(a.x + b.x, 0.f);
        a.y = fmaxf(a.y + b.y, 0.f);
        a.z = fmaxf(a.z + b.z, 0.f);
        a.w = fmaxf(a.w + b.w, 0.f);
        ((float4*)out)[idx] = a;
    }
}

// ---------- stats partial (input h_e already bias+relu'd) ------------------
__global__ __launch_bounds__(256) void k_stats_partial(
    const float* __restrict__ h_e,
    const float* __restrict__ w2,
    float* __restrict__ psum)
{
    __shared__ float hs[16][256];
    int mg = blockIdx.x >> 4;
    int ks = blockIdx.x & 15;
    int t = threadIdx.x;

    for (int i = t; i < 16 * 256; i += 256) {
        int mm = i >> 8, kk = i & 255;
        hs[mm][kk] = h_e[(size_t)(mg * 16 + mm) * 4096 + ks * 256 + kk];
    }
    __syncthreads();

    int n = t & 127, mh = t >> 7;
    float acc[8] = {0.f,0.f,0.f,0.f,0.f,0.f,0.f,0.f};
    const float* w2p = w2 + (size_t)(ks * 256) * 128 + n;
    for (int k = 0; k < 256; ++k) {
        float wv = w2p[(size_t)k * 128];
        #pragma unroll
        for (int mm = 0; mm < 8; ++mm)
            acc[mm] += hs[mh * 8 + mm][k] * wv;
    }
    #pragma unroll
    for (int mm = 0; mm < 8; ++mm) {
        int m = mg * 16 + mh * 8 + mm;
        psum[((size_t)m * 16 + ks) * 128 + n] = acc[mm];
    }
}

// ---------- mid2 (unchanged) ----------
__global__ __launch_bounds__(256) void k_mid2(
    const float* __restrict__ psum,
    const float* __restrict__ enc_b2,
    const float* __restrict__ noise_z,
    const float* __restrict__ dec_w1, const float* __restrict__ dec_b1,
    const float* __restrict__ dec_w2, const float* __restrict__ dec_b2,
    float* __restrict__ mean_out, float* __restrict__ logvar_out,
    unsigned short* __restrict__ h2bf)
{
    __shared__ float st[128];
    __shared__ float z_s[64];
    __shared__ float h1_s[32];

    int m = blockIdx.x >> 2, ch = blockIdx.x & 3;
    int t = threadIdx.x;

    if (t < 128) {
        float a = enc_b2[t];
        #pragma unroll 4
        for (int ks = 0; ks < 16; ++ks)
            a += psum[((size_t)m * 16 + ks) * 128 + t];
        st[t] = fmaxf(a, 0.f);
    }
    __syncthreads();

    if (t < 64) {
        float mean = st[t], lv = st[t + 64];
        if (ch == 0) {
            mean_out[(size_t)m * 64 + t]   = mean;
            logvar_out[(size_t)m * 64 + t] = lv;
        }
        z_s[t] = noise_z[(size_t)m * 64 + t] * expf(0.5f * lv) + mean;
    }
    __syncthreads();

    if (t < 32) {
        float a = dec_b1[t];
        #pragma unroll 8
        for (int k = 0; k < 64; ++k) a += z_s[k] * dec_w1[k * 32 + t];
        h1_s[t] = fmaxf(a, 0.f);
    }
    __syncthreads();

    #pragma unroll
    for (int j = 0; j < 4; ++j) {
        int nn = ch * 1024 + j * 256 + t;
        float a = dec_b2[nn];
        #pragma unroll 8
        for (int k = 0; k < 32; ++k)
            a += h1_s[k] * dec_w2[(size_t)k * 4096 + nn];
        h2bf[(size_t)m * 4096 + nn] = f2bf(fmaxf(a, 0.f));
    }
}

extern "C" void kernel_launch(void* const* d_in, const int* in_sizes, int n_in,
                              void* d_out, int out_size, void* d_ws, size_t ws_size,
                              hipStream_t stream) {
    const float* x            = (const float*)d_in[0];
    const float* noise_little = (const float*)d_in[1];
    const float* noise_z      = (const float*)d_in[2];
    const float* le_w1        = (const float*)d_in[3];
    const float* le_b1        = (const float*)d_in[4];
    const float* le_w2        = (const float*)d_in[5];
    const float* le_b2        = (const float*)d_in[6];
    const float* ld_w1        = (const float*)d_in[7];
    const float* ld_b1        = (const float*)d_in[8];
    const float* ld_w2        = (const float*)d_in[9];
    const float* ld_b2        = (const float*)d_in[10];
    const float* enc_w1       = (const float*)d_in[11];
    const float* enc_b1       = (const float*)d_in[12];
    const float* enc_w2       = (const float*)d_in[13];
    const float* enc_b2       = (const float*)d_in[14];
    const float* dec_w1       = (const float*)d_in[15];
    const float* dec_b1       = (const float*)d_in[16];
    const float* dec_w2       = (const float*)d_in[17];
    const float* dec_b2       = (const float*)d_in[18];
    const float* dec_w3       = (const float*)d_in[19];
    const float* dec_b3       = (const float*)d_in[20];

    float* out = (float*)d_out;
    float* latent = out;                       // 1,806,336
    float* mean   = latent + 1806336;          // 16,384
    float* logvar = mean + 16384;              // 16,384
    float* nli    = logvar + 16384;            // 1,806,336
    float* img    = nli + 1806336;             // 3,145,728

    float* h_e = latent;   // parked; overwritten by GEMM2 reduce later

    unsigned short* nli_bf = (unsigned short*)d_ws;                   // 3,612,672 B
    float* psum = (float*)((char*)d_ws + 3612672);                    // 2,097,152 B
    unsigned short* h2bf = (unsigned short*)((char*)d_ws + 5709824);  // 2,097,152 B
    float* parts = (float*)((char*)d_ws + 7806976);                   // up to 28.9 MB

    // ws needed for partials path: 7,806,976 + 4*256*7056*4 = 36,708,352 B
    const bool wsPath = (ws_size >= 36708352u);

    // 1) patches + little_encode + reparam (MFMA)
    k_little_encode_mfma<<<882, 256, 0, stream>>>(
        x, noise_little, le_w1, le_b1, le_w2, le_b2, nli, nli_bf);

    if (wsPath) {
        // 2) partials = nli @ enc_w1 (S=4), then reduce+bias+relu -> h_e
        k_gemm_splitk<1><<<dim3(64, 2, 4), 256, 0, stream>>>(
            nli_bf, enc_w1, parts, 4096, 7056, 28);
        k_reduce_bias_relu<<<1024, 256, 0, stream>>>(
            parts, enc_b1, h_e, 4, 4096);
    } else {
        hipMemsetAsync(h_e, 0, (size_t)256 * 4096 * 4, stream);
        k_gemm_splitk<0><<<dim3(64, 2, 8), 256, 0, stream>>>(
            nli_bf, enc_w1, h_e, 4096, 7056, 14);
        k_reduce_bias_relu<<<1024, 256, 0, stream>>>(
            h_e, enc_b1, h_e, 1, 4096);   // in-place bias+relu
    }

    // 3a) psum partials  3b) reduce + reparam + dec1 + dec2
    k_stats_partial<<<256, 256, 0, stream>>>(h_e, enc_w2, psum);
    k_mid2<<<1024, 256, 0, stream>>>(
        psum, enc_b2, noise_z, dec_w1, dec_b1, dec_w2, dec_b2,
        mean, logvar, h2bf);

    if (wsPath) {
        // 4) partials = h2 @ dec_w3 (S=4), reduce+bias+relu -> latent
        k_gemm_splitk<1><<<dim3(111, 2, 4), 256, 0, stream>>>(
            h2bf, dec_w3, parts, 7056, 4096, 16);
        k_reduce_bias_relu<<<1764, 256, 0, stream>>>(
            parts, dec_b3, latent, 4, 7056);
    } else {
        hipMemsetAsync(latent, 0, (size_t)1806336 * 4, stream);
        k_gemm_splitk<0><<<dim3(111, 2, 8), 256, 0, stream>>>(
            h2bf, dec_w3, latent, 7056, 4096, 8);
        k_reduce_bias_relu<<<1764, 256, 0, stream>>>(
            latent, dec_b3, latent, 1, 7056);
    }

    // 5) little_decode + canvas (MFMA)
    k_little_decode_mfma<<<338, 256, 0, stream>>>(
        latent, ld_w1, ld_b1, ld_w2, ld_b2, img);
}